// Round 6
// baseline (769.044 us; speedup 1.0000x reference)
//
#include <hip/hip_runtime.h>

// Problem constants
static constexpr int NG   = 100000;
static constexpr int NC   = 2000;
static constexpr int D    = 256;
static constexpr int NE   = 1000000;
static constexpr int NOUTD= 64;
static constexpr int KCAT = 768;          // concatenated K: [agg | x | v]

typedef __bf16 bf16x8 __attribute__((ext_vector_type(8)));
typedef float  f32x4  __attribute__((ext_vector_type(4)));

__device__ __forceinline__ unsigned short f2bf(float f) {
    unsigned u = __float_as_uint(f);
    u += 0x7fffu + ((u >> 16) & 1u);   // RNE
    return (unsigned short)(u >> 16);
}
__device__ __forceinline__ float bflo(unsigned x) { return __uint_as_float((x & 0xffffu) << 16); }
__device__ __forceinline__ float bfhi(unsigned x) { return __uint_as_float(x & 0xffff0000u); }

__device__ __forceinline__ void async16(const void* g, void* l) {
    __builtin_amdgcn_global_load_lds(
        (const __attribute__((address_space(1))) void*)g,
        (__attribute__((address_space(3))) void*)l, 16, 0, 0);
}

// ---------------- prep (cells only): f32 -> bf16 x and v=x*w ----------------
__global__ void prep_x(const float* __restrict__ x, const float* __restrict__ w,
                       unsigned short* __restrict__ dx, unsigned short* __restrict__ dv,
                       long stride, int rows) {
    int i = blockIdx.x * blockDim.x + threadIdx.x;   // one per 4 elements
    if (i >= rows * (D / 4)) return;
    int row = i >> 6, c4 = (i & 63) * 4;
    float4 xv = *reinterpret_cast<const float4*>(x + (size_t)row * D + c4);
    float wv = w[row];
    uint2 ox, ov;
    ox.x = (unsigned)f2bf(xv.x) | ((unsigned)f2bf(xv.y) << 16);
    ox.y = (unsigned)f2bf(xv.z) | ((unsigned)f2bf(xv.w) << 16);
    ov.x = (unsigned)f2bf(xv.x * wv) | ((unsigned)f2bf(xv.y * wv) << 16);
    ov.y = (unsigned)f2bf(xv.z * wv) | ((unsigned)f2bf(xv.w * wv) << 16);
    *reinterpret_cast<uint2*>(dx + (size_t)row * stride + c4) = ox;
    *reinterpret_cast<uint2*>(dv + (size_t)row * stride + c4) = ov;
}

// ---------------- build concatenated bf16 weights [256][768] + bias sums ----
__global__ void build_wcat(const float* __restrict__ Wa,  const float* __restrict__ Wra,
                           const float* __restrict__ Wrb, const float* __restrict__ Wb,
                           const float* __restrict__ ba,  const float* __restrict__ bb,
                           unsigned short* __restrict__ wout, float* __restrict__ bsum) {
    int i = blockIdx.x * blockDim.x + threadIdx.x;
    if (i >= D * D) return;
    int n = i >> 8, k = i & 255;
    wout[(size_t)n * KCAT + k]        = f2bf(Wa[i]);
    wout[(size_t)n * KCAT + 256 + k]  = f2bf(Wra[i] + Wrb[i]);
    wout[(size_t)n * KCAT + 512 + k]  = f2bf(Wb[i]);
    if (i < D) bsum[i] = ba[i] + bb[i];
}

// ---------------- fine counts: LDS-hist for cells, global atomics for genes -
static constexpr int CE_CHUNK = 8192;
__global__ __launch_bounds__(256) void count_edges(const int* __restrict__ dst_g2c,
                                                   const int* __restrict__ dst_c2g,
                                                   int* __restrict__ cnt_c,
                                                   int* __restrict__ cnt_g) {
    __shared__ int h[NC];
    for (int i = threadIdx.x; i < NC; i += 256) h[i] = 0;
    __syncthreads();
    int base = blockIdx.x * CE_CHUNK;
#pragma unroll 4
    for (int t = 0; t < CE_CHUNK / 256; ++t) {
        int e = base + t * 256 + threadIdx.x;
        if (e < NE) {
            atomicAdd(&h[dst_g2c[e]], 1);
            atomicAdd(&cnt_g[dst_c2g[e]], 1);
        }
    }
    __syncthreads();
    for (int i = threadIdx.x; i < NC; i += 256)
        if (h[i]) atomicAdd(&cnt_c[i], h[i]);
}

static constexpr int SCAN_NB = 256;
static constexpr int SCAN_NT = 256;

// fused g+c scans: blocks [0,256) handle (cntA,nA), [256,512) handle (cntB,nB)
__global__ __launch_bounds__(256) void scan_phaseA(const int* __restrict__ cntA, int nA,
                                                   int* __restrict__ partA,
                                                   const int* __restrict__ cntB, int nB,
                                                   int* __restrict__ partB) {
    __shared__ int sd[SCAN_NT];
    const int* cnt; int n; int* partials; int b;
    if (blockIdx.x < SCAN_NB) { cnt = cntA; n = nA; partials = partA; b = blockIdx.x; }
    else { cnt = cntB; n = nB; partials = partB; b = blockIdx.x - SCAN_NB; }
    int chunk = (n + SCAN_NB - 1) / SCAN_NB;
    int ts = (chunk + SCAN_NT - 1) / SCAN_NT;
    int bstart = b * chunk;
    int bend = bstart + chunk; if (bend > n) bend = n;
    int start = bstart + threadIdx.x * ts;
    int end = start + ts; if (end > bend) end = bend;
    int sum = 0;
    for (int j = start; j < end; ++j) sum += cnt[j];
    sd[threadIdx.x] = sum;
    __syncthreads();
    for (int off = SCAN_NT / 2; off > 0; off >>= 1) {
        if (threadIdx.x < off) sd[threadIdx.x] += sd[threadIdx.x + off];
        __syncthreads();
    }
    if (threadIdx.x == 0) partials[b] = sd[0];
}

__global__ __launch_bounds__(256) void scan_phaseB(const int* __restrict__ partA,
                                                   int* __restrict__ boffA,
                                                   int* __restrict__ rpA, int nA,
                                                   const int* __restrict__ partB,
                                                   int* __restrict__ boffB,
                                                   int* __restrict__ rpB, int nB) {
    __shared__ int sd[SCAN_NB];
    const int* partials; int* blockoff; int* rp; int n;
    if (blockIdx.x == 0) { partials = partA; blockoff = boffA; rp = rpA; n = nA; }
    else { partials = partB; blockoff = boffB; rp = rpB; n = nB; }
    int t = threadIdx.x;
    int v = partials[t];
    sd[t] = v;
    __syncthreads();
    for (int off = 1; off < SCAN_NB; off <<= 1) {
        int u = (t >= off) ? sd[t - off] : 0;
        __syncthreads();
        sd[t] += u;
        __syncthreads();
    }
    blockoff[t] = sd[t] - v;
    if (t == SCAN_NB - 1) rp[n] = sd[SCAN_NB - 1];
}

__global__ __launch_bounds__(256) void scan_phaseC(const int* __restrict__ cntA, int nA,
                                                   const int* __restrict__ boffA,
                                                   int* __restrict__ rpA,
                                                   const int* __restrict__ cntB, int nB,
                                                   const int* __restrict__ boffB,
                                                   int* __restrict__ rpB) {
    __shared__ int sd[SCAN_NT];
    const int* cnt; int n; const int* blockoff; int* rp; int b;
    if (blockIdx.x < SCAN_NB) { cnt = cntA; n = nA; blockoff = boffA; rp = rpA; b = blockIdx.x; }
    else { cnt = cntB; n = nB; blockoff = boffB; rp = rpB; b = blockIdx.x - SCAN_NB; }
    int chunk = (n + SCAN_NB - 1) / SCAN_NB;
    int ts = (chunk + SCAN_NT - 1) / SCAN_NT;
    int bstart = b * chunk;
    int bend = bstart + chunk; if (bend > n) bend = n;
    int start = bstart + threadIdx.x * ts;
    int end = start + ts; if (end > bend) end = bend;
    int sum = 0;
    for (int j = start; j < end; ++j) sum += cnt[j];
    sd[threadIdx.x] = sum;
    __syncthreads();
    for (int off = 1; off < SCAN_NT; off <<= 1) {
        int u = (threadIdx.x >= off) ? sd[threadIdx.x - off] : 0;
        __syncthreads();
        sd[threadIdx.x] += u;
        __syncthreads();
    }
    int run = blockoff[b] + sd[threadIdx.x] - sum;
    for (int j = start; j < end; ++j) { rp[j] = run; run += cnt[j]; }
}

// ---------------- two-level binned CSR fill ---------------------------------
__global__ void init_coarse(const int* __restrict__ rp_c, const int* __restrict__ rp_g,
                            int* __restrict__ cc, int* __restrict__ cg) {
    int t = threadIdx.x;
    int ic = t << 3;  if (ic > NC) ic = NC;
    int ig = t << 9;  if (ig > NG) ig = NG;
    cc[t] = rp_c[ic];
    cg[t] = rp_g[ig];
}

// pass1 (fused c/g via blockIdx.y): scatter edges into 256 coarse buckets
static constexpr int P1_CHUNK = 8192;
__global__ __launch_bounds__(256) void bucket_pass1(
        const int* __restrict__ srcA, const int* __restrict__ dstA, const float* __restrict__ wA,
        int* __restrict__ curA, int2* __restrict__ outA,
        const int* __restrict__ srcB, const int* __restrict__ dstB, const float* __restrict__ wB,
        int* __restrict__ curB, int2* __restrict__ outB) {
    __shared__ int hist[256], lcur[256], gbase[256];
    const int* src; const int* dst; const float* w; int* coarse_cur; int2* out;
    int shift, packshift;
    if (blockIdx.y == 0) { src = srcA; dst = dstA; w = wA; coarse_cur = curA; out = outA; shift = 3; packshift = 17; }
    else { src = srcB; dst = dstB; w = wB; coarse_cur = curB; out = outB; shift = 9; packshift = 11; }
    int tid = threadIdx.x;
    hist[tid] = 0;
    __syncthreads();
    int base = blockIdx.x * P1_CHUNK;
    int mybin[P1_CHUNK / 256];
#pragma unroll
    for (int t = 0; t < P1_CHUNK / 256; ++t) {
        int e = base + t * 256 + tid;
        if (e < NE) {
            int b = dst[e] >> shift;
            mybin[t] = b;
            atomicAdd(&hist[b], 1);
        } else mybin[t] = -1;
    }
    __syncthreads();
    int v = hist[tid];
    gbase[tid] = v ? atomicAdd(&coarse_cur[tid], v) : 0;
    lcur[tid] = 0;
    __syncthreads();
#pragma unroll
    for (int t = 0; t < P1_CHUNK / 256; ++t) {
        int b = mybin[t];
        if (b < 0) continue;
        int e = base + t * 256 + tid;
        int pos = gbase[b] + atomicAdd(&lcur[b], 1);
        int dl = dst[e] & ((1 << shift) - 1);
        out[pos] = make_int2(src[e] | (dl << packshift), __float_as_int(w[e]));
    }
}

// pass2 (fused): fine scatter within each bucket; cells = blocks [0,250), genes after
static constexpr int P2_CBLK = NC / 8;                 // 250
static constexpr int P2_GBLK = (NG + 511) / 512;       // 196
__global__ __launch_bounds__(256) void bucket_pass2(
        const int2* __restrict__ stC, const int* __restrict__ rpC, int2* __restrict__ outC,
        const int2* __restrict__ stG, const int* __restrict__ rpG, int2* __restrict__ outG) {
    __shared__ int cur[512];
    const int2* staged; const int* rp; int2* out; int shift, packshift, ndst, b;
    if (blockIdx.x < P2_CBLK) { staged = stC; rp = rpC; out = outC; shift = 3; packshift = 17; ndst = NC; b = blockIdx.x; }
    else { staged = stG; rp = rpG; out = outG; shift = 9; packshift = 11; ndst = NG; b = blockIdx.x - P2_CBLK; }
    int nf = 1 << shift;
    int d0 = b << shift;
    for (int f = threadIdx.x; f < nf; f += 256) {
        int d = d0 + f;
        cur[f] = (d < ndst) ? rp[d] : 0;
    }
    __syncthreads();
    int hi = (b + 1) << shift; if (hi > ndst) hi = ndst;
    int j0 = rp[d0], j1 = rp[hi];
    for (int j = j0 + threadIdx.x; j < j1; j += 256) {
        int2 e = staged[j];
        int f = ((unsigned)e.x) >> packshift;
        int pos = atomicAdd(&cur[f], 1);
        out[pos] = make_int2(e.x & ((1 << packshift) - 1), e.y);
    }
}

// ---------------- per-cell sort of edge segments by src gene ----------------
__global__ __launch_bounds__(256) void sort_cell_edges(const int* __restrict__ rp,
                                                       int2* __restrict__ ec) {
    __shared__ int2 s[1024];
    int c = blockIdx.x;
    int j0 = rp[c], j1 = rp[c + 1];
    int n = j1 - j0;
    if (n <= 1 || n > 1024) return;   // skip = perf-only fallback
    for (int i = threadIdx.x; i < 1024; i += 256)
        s[i] = (i < n) ? ec[j0 + i] : make_int2(0x7fffffff, 0);
    __syncthreads();
    for (int k = 2; k <= 1024; k <<= 1) {
        for (int jj = k >> 1; jj > 0; jj >>= 1) {
#pragma unroll
            for (int t = 0; t < 4; ++t) {
                int i = threadIdx.x + t * 256;
                int ixj = i ^ jj;
                if (ixj > i) {
                    int2 a = s[i], b = s[ixj];
                    bool up = ((i & k) == 0);
                    if ((a.x > b.x) == up) { s[i] = b; s[ixj] = a; }
                }
            }
            __syncthreads();
        }
    }
    for (int i = threadIdx.x; i < n; i += 256) ec[j0 + i] = s[i];
}

// ---------------- fused gene layer: agg + convert + GEMM + relu -------------
// Per block: 64 gene rows x all 256 N cols. LDS: A-seg [64][256] bf16 (XOR-
// swizzled 16B chunks) + B-tile [256][64]. K processed as 3 segments of 256
// (agg -> Wrel1 into accA; x -> Wroot_comb into accA and Wrel2 into accV;
// (x*w)@Wrel2^T == w_row * (x@Wrel2^T) so the v-copy of A never exists).
// Side-writes bf16 x_gene (xg0b) for layer-1 agg_cell.
__global__ __launch_bounds__(256, 2) void gene_fused(
        const float* __restrict__ x_gene,        // [NG][256] f32
        const float* __restrict__ w_gg,          // [NG]
        const int* __restrict__ rp,              // gene CSR rowptr
        const int2* __restrict__ eg,             // (src cell, weight) per edge
        const unsigned short* __restrict__ xc,   // cell bf16 rows
        long sstride,
        const unsigned short* __restrict__ W,    // [256][768]: rel1|rootc|rel2
        const float* __restrict__ bias,          // [256]
        unsigned short* __restrict__ xg0b,       // side out: bf16 x [NG][256]
        unsigned short* __restrict__ xg1) {      // out [NG][256]
    __shared__ unsigned short As[64 * 256];      // 32 KB
    __shared__ unsigned short Bs[256 * 64];      // 32 KB
    int tid = threadIdx.x;
    int wv = tid >> 6, ln = tid & 63;
    int lm = ln & 15, lq = ln >> 4;
    int m0 = blockIdx.x * 64;

    f32x4 accA[4][4], accV[4][4];
#pragma unroll
    for (int i = 0; i < 4; ++i)
#pragma unroll
        for (int j = 0; j < 4; ++j) { accA[i][j] = f32x4{0,0,0,0}; accV[i][j] = f32x4{0,0,0,0}; }

    // one K-segment (256 cols of W at segoff) against resident As
    auto run_seg = [&](int segoff, f32x4 (&acc)[4][4]) {
        for (int kb = 0; kb < 4; ++kb) {
#pragma unroll
            for (int tt = 0; tt < 8; ++tt) {
                int ci = tt * 256 + tid;
                int n = ci >> 3, s = ci & 7;
                int cg = s ^ (n & 7);
                async16(W + (size_t)n * KCAT + segoff + kb * 64 + cg * 8,
                        (unsigned char*)Bs + ci * 16);
            }
            __syncthreads();
#pragma unroll
            for (int kk = 0; kk < 2; ++kk) {
                bf16x8 a[4], b[4];
#pragma unroll
                for (int i = 0; i < 4; ++i) {
                    int r = i * 16 + lm;
                    int slot = kb * 8 + ((kk * 4 + lq) ^ (r & 7));
                    a[i] = *reinterpret_cast<const bf16x8*>(As + r * 256 + slot * 8);
                }
#pragma unroll
                for (int j = 0; j < 4; ++j) {
                    int n = wv * 64 + j * 16 + lm;
                    int slot = (kk * 4 + lq) ^ (n & 7);
                    b[j] = *reinterpret_cast<const bf16x8*>(Bs + n * 64 + slot * 8);
                }
#pragma unroll
                for (int i = 0; i < 4; ++i)
#pragma unroll
                    for (int j = 0; j < 4; ++j)
                        acc[i][j] = __builtin_amdgcn_mfma_f32_16x16x32_bf16(a[i], b[j], acc[i][j], 0, 0, 0);
            }
            __syncthreads();
        }
    };

    // ---- phase 1: As = agg rows (gather from L2-resident cell matrix) ----
    {
        int cchunk = ln >> 1;                 // 16B chunk 0..31 of the row
        int kb = cchunk >> 3, cw = cchunk & 7;
        int coff = ln * 4;                    // 4 bf16 cols per lane
        for (int rr = wv * 16; rr < wv * 16 + 16; ++rr) {
            float a0 = 0.f, a1 = 0.f, a2 = 0.f, a3 = 0.f;
            int row = m0 + rr;
            if (row < NG) {
                int j0 = rp[row], j1 = rp[row + 1];
                int j = j0, n4 = j0 + ((j1 - j0) & ~3);
                for (; j < n4; j += 4) {
                    int2 e1 = eg[j], e2 = eg[j + 1], e3 = eg[j + 2], e4 = eg[j + 3];
                    uint2 p1 = *reinterpret_cast<const uint2*>(xc + (size_t)e1.x * sstride + coff);
                    uint2 p2 = *reinterpret_cast<const uint2*>(xc + (size_t)e2.x * sstride + coff);
                    uint2 p3 = *reinterpret_cast<const uint2*>(xc + (size_t)e3.x * sstride + coff);
                    uint2 p4 = *reinterpret_cast<const uint2*>(xc + (size_t)e4.x * sstride + coff);
                    float w1 = __int_as_float(e1.y), w2 = __int_as_float(e2.y);
                    float w3 = __int_as_float(e3.y), w4 = __int_as_float(e4.y);
                    a0 += w1 * bflo(p1.x) + w2 * bflo(p2.x) + w3 * bflo(p3.x) + w4 * bflo(p4.x);
                    a1 += w1 * bfhi(p1.x) + w2 * bfhi(p2.x) + w3 * bfhi(p3.x) + w4 * bfhi(p4.x);
                    a2 += w1 * bflo(p1.y) + w2 * bflo(p2.y) + w3 * bflo(p3.y) + w4 * bflo(p4.y);
                    a3 += w1 * bfhi(p1.y) + w2 * bfhi(p2.y) + w3 * bfhi(p3.y) + w4 * bfhi(p4.y);
                }
                for (; j < j1; ++j) {
                    int2 e = eg[j];
                    float w = __int_as_float(e.y);
                    uint2 pk = *reinterpret_cast<const uint2*>(xc + (size_t)e.x * sstride + coff);
                    a0 += w * bflo(pk.x); a1 += w * bfhi(pk.x);
                    a2 += w * bflo(pk.y); a3 += w * bfhi(pk.y);
                }
            }
            int slot = kb * 8 + (cw ^ (rr & 7));
            uint2 val;
            val.x = (unsigned)f2bf(a0) | ((unsigned)f2bf(a1) << 16);
            val.y = (unsigned)f2bf(a2) | ((unsigned)f2bf(a3) << 16);
            *reinterpret_cast<uint2*>(
                reinterpret_cast<unsigned char*>(As) + ((rr * 32 + slot) << 4) + ((ln & 1) << 3)) = val;
        }
    }
    __syncthreads();
    run_seg(0, accA);                 // agg @ Wrel1^T

    // ---- phase 2: As = x rows (f32 load, bf16 convert, side-write) ----
#pragma unroll
    for (int tt = 0; tt < 16; ++tt) {
        int flat = tt * 256 + tid;          // float4 units over [64][64]
        int r = flat >> 6, c4g = flat & 63;
        int row = m0 + r;
        uint2 val = {0u, 0u};
        if (row < NG) {
            float4 xv = *reinterpret_cast<const float4*>(x_gene + (size_t)row * D + c4g * 4);
            val.x = (unsigned)f2bf(xv.x) | ((unsigned)f2bf(xv.y) << 16);
            val.y = (unsigned)f2bf(xv.z) | ((unsigned)f2bf(xv.w) << 16);
            *reinterpret_cast<uint2*>(xg0b + (size_t)row * D + c4g * 4) = val;
        }
        int chunk = c4g >> 1, kb = chunk >> 3, cw = chunk & 7;
        int slot = kb * 8 + (cw ^ (r & 7));
        *reinterpret_cast<uint2*>(
            reinterpret_cast<unsigned char*>(As) + ((r * 32 + slot) << 4) + ((c4g & 1) << 3)) = val;
    }
    __syncthreads();
    run_seg(256, accA);               // x @ (Wroot1+Wroot2)^T
    run_seg(512, accV);               // x @ Wrel2^T   (scaled by w_gg at epilogue)

    // ---- epilogue ----
#pragma unroll
    for (int i = 0; i < 4; ++i) {
#pragma unroll
        for (int r4 = 0; r4 < 4; ++r4) {
            int rloc = i * 16 + lq * 4 + r4;
            int row = m0 + rloc;
            if (row >= NG) continue;
            float wr = w_gg[row];
#pragma unroll
            for (int j = 0; j < 4; ++j) {
                int col = wv * 64 + j * 16 + lm;
                float v = accA[i][j][r4] + wr * accV[i][j][r4] + bias[col];
                v = v > 0.f ? v : 0.f;
                xg1[(size_t)row * D + col] = f2bf(v);
            }
        }
    }
}

// ---------------- cell aggregation: one block per cell, LDS reduce ----------
__global__ __launch_bounds__(256) void agg_cell(const int* __restrict__ rp,
                                                const int2* __restrict__ ec,
                                                const unsigned short* __restrict__ src, long sstride,
                                                unsigned short* __restrict__ out, long ostride) {
    __shared__ float red[4][D];
    int c = blockIdx.x;
    int wv = threadIdx.x >> 6, ln = threadIdx.x & 63;
    int j0 = rp[c], j1 = rp[c + 1];
    float a0 = 0.f, a1 = 0.f, a2 = 0.f, a3 = 0.f;
    int npair = (j1 - j0) & ~7;        // chunks of 8 = 4 waves x 2 edges
    for (int j = j0 + wv * 2; j < j0 + npair; j += 8) {
        int2 e1 = ec[j], e2 = ec[j + 1];
        float w1 = __int_as_float(e1.y), w2 = __int_as_float(e2.y);
        uint2 p1 = *reinterpret_cast<const uint2*>(src + (size_t)e1.x * sstride + ln * 4);
        uint2 p2 = *reinterpret_cast<const uint2*>(src + (size_t)e2.x * sstride + ln * 4);
        a0 += w1 * bflo(p1.x) + w2 * bflo(p2.x);
        a1 += w1 * bfhi(p1.x) + w2 * bfhi(p2.x);
        a2 += w1 * bflo(p1.y) + w2 * bflo(p2.y);
        a3 += w1 * bfhi(p1.y) + w2 * bfhi(p2.y);
    }
    for (int j = j0 + npair + wv; j < j1; j += 4) {
        int2 e = ec[j];
        float w = __int_as_float(e.y);
        uint2 pk = *reinterpret_cast<const uint2*>(src + (size_t)e.x * sstride + ln * 4);
        a0 += w * bflo(pk.x); a1 += w * bfhi(pk.x);
        a2 += w * bflo(pk.y); a3 += w * bfhi(pk.y);
    }
    red[wv][ln * 4 + 0] = a0; red[wv][ln * 4 + 1] = a1;
    red[wv][ln * 4 + 2] = a2; red[wv][ln * 4 + 3] = a3;
    __syncthreads();
    int col = threadIdx.x;
    float s = red[0][col] + red[1][col] + red[2][col] + red[3][col];
    out[(size_t)c * ostride + col] = f2bf(s);
}

// ---------------- m97-style GEMM (cells): relu(A[M,768] @ W^T + bias) -------
__global__ __launch_bounds__(256, 2) void gemm_tile(
        const unsigned short* __restrict__ A,    // [M][768]
        const unsigned short* __restrict__ W,    // [256][768]
        const float* __restrict__ bias,          // [256]
        const float* __restrict__ wrow,          // nullable per-row scale for vout
        unsigned short* __restrict__ xout, long xstride,
        unsigned short* __restrict__ vout,       // nullable, same stride
        int M) {
    __shared__ unsigned short As[128 * 64];
    __shared__ unsigned short Bs[128 * 64];
    int tid = threadIdx.x;
    int wv = tid >> 6, ln = tid & 63;
    int lm = ln & 15, lq = ln >> 4;
    int m0 = blockIdx.x * 128;
    int nb = blockIdx.y * 128;
    int m0w = m0 + (wv >> 1) * 64;
    int n0w = nb + (wv & 1) * 64;

    f32x4 acc[4][4];
#pragma unroll
    for (int i = 0; i < 4; ++i)
#pragma unroll
        for (int j = 0; j < 4; ++j) acc[i][j] = f32x4{0.f, 0.f, 0.f, 0.f};

    for (int k0 = 0; k0 < KCAT; k0 += 64) {
#pragma unroll
        for (int t = 0; t < 4; ++t) {
            int ci = t * 256 + tid;
            int r = ci >> 3, s = ci & 7;
            int cg = s ^ (r & 7);
            int row = m0 + r; if (row >= M) row = M - 1;
            async16(A + (size_t)row * KCAT + k0 + cg * 8,
                    (unsigned char*)As + ci * 16);
        }
#pragma unroll
        for (int t = 0; t < 4; ++t) {
            int ci = t * 256 + tid;
            int r = ci >> 3, s = ci & 7;
            int cg = s ^ (r & 7);
            async16(W + (size_t)(nb + r) * KCAT + k0 + cg * 8,
                    (unsigned char*)Bs + ci * 16);
        }
        __syncthreads();
#pragma unroll
        for (int kk = 0; kk < 2; ++kk) {
            bf16x8 a[4], b[4];
#pragma unroll
            for (int i = 0; i < 4; ++i) {
                int r = (wv >> 1) * 64 + i * 16 + lm;
                int c = kk * 4 + lq;
                int s = c ^ (r & 7);
                a[i] = *reinterpret_cast<const bf16x8*>(As + (r * 8 + s) * 8);
            }
#pragma unroll
            for (int j = 0; j < 4; ++j) {
                int r = (wv & 1) * 64 + j * 16 + lm;
                int c = kk * 4 + lq;
                int s = c ^ (r & 7);
                b[j] = *reinterpret_cast<const bf16x8*>(Bs + (r * 8 + s) * 8);
            }
#pragma unroll
            for (int i = 0; i < 4; ++i)
#pragma unroll
                for (int j = 0; j < 4; ++j)
                    acc[i][j] = __builtin_amdgcn_mfma_f32_16x16x32_bf16(a[i], b[j], acc[i][j], 0, 0, 0);
        }
        __syncthreads();
    }

#pragma unroll
    for (int i = 0; i < 4; ++i) {
#pragma unroll
        for (int r4 = 0; r4 < 4; ++r4) {
            int rr = m0w + i * 16 + lq * 4 + r4;
            if (rr >= M) continue;
            float wr = wrow ? wrow[rr] : 0.f;
#pragma unroll
            for (int j = 0; j < 4; ++j) {
                int col = n0w + j * 16 + lm;
                float v = acc[i][j][r4] + bias[col];
                v = v > 0.f ? v : 0.f;
                xout[(size_t)rr * xstride + col] = f2bf(v);
                if (vout) vout[(size_t)rr * xstride + col] = f2bf(v * wr);
            }
        }
    }
}

// ---------------- final projection: out = xc2 @ Wout^T + bout (fp32) --------
__global__ void out_kernel(const unsigned short* __restrict__ xc, const float* __restrict__ Wout,
                           const float* __restrict__ bout, float* __restrict__ out) {
    __shared__ float srow[4][D];
    int r = threadIdx.x >> 6;
    int o = threadIdx.x & 63;
    int c = blockIdx.x * 4 + r;
    for (int t = threadIdx.x; t < 4 * D; t += 256) {
        int rr = blockIdx.x * 4 + (t >> 8);
        unsigned short h = xc[(size_t)rr * D + (t & 255)];
        srow[t >> 8][t & 255] = __uint_as_float(((unsigned)h) << 16);
    }
    __syncthreads();
    float s = 0.f;
    const float* wo = Wout + o * D;
    for (int k = 0; k < D; ++k) s += srow[r][k] * wo[k];
    out[(size_t)c * NOUTD + o] = s + bout[o];
}

// ---------------- orchestration ---------------------------------------------
extern "C" void kernel_launch(void* const* d_in, const int* in_sizes, int n_in,
                              void* d_out, int out_size, void* d_ws, size_t ws_size,
                              hipStream_t stream) {
    const float* x_gene = (const float*)d_in[0];
    const float* x_cell = (const float*)d_in[1];
    const int*   src_g2c = (const int*)d_in[2];
    const int*   dst_g2c = (const int*)d_in[3];
    const int*   src_c2g = (const int*)d_in[4];
    const int*   dst_c2g = (const int*)d_in[5];
    const float* w_g2c = (const float*)d_in[8];
    const float* w_c2g = (const float*)d_in[9];
    const float* w_gg  = (const float*)d_in[10];
    const float* w_cc  = (const float*)d_in[11];
    const float* Wrel  = (const float*)d_in[12];
    const float* brel  = (const float*)d_in[13];
    const float* Wroot = (const float*)d_in[14];
    const float* Wout  = (const float*)d_in[15];
    const float* bout  = (const float*)d_in[16];
    float* out = (float*)d_out;

    char* p = (char*)d_ws;
    auto alloc = [&](size_t bytes) -> char* {
        char* r = p;
        p += (bytes + 255) & ~(size_t)255;
        return r;
    };

    unsigned short* xg0b    = (unsigned short*)alloc((size_t)NG * D * 2);
    unsigned short* xg1     = (unsigned short*)alloc((size_t)NG * D * 2);
    unsigned short* Acat_c0 = (unsigned short*)alloc((size_t)NC * KCAT * 2);
    unsigned short* Acat_c1 = (unsigned short*)alloc((size_t)NC * KCAT * 2);
    unsigned short* xc2     = (unsigned short*)alloc((size_t)NC * D * 2);
    int* rp_g  = (int*)alloc((NG + 1) * 4);
    int* cnt_g = (int*)alloc(NG * 4);
    int* rp_c  = (int*)alloc((NC + 1) * 4);
    int* cnt_c = (int*)alloc(NC * 4);
    int2* ec = (int2*)alloc((size_t)NE * 8);       // g2c edges grouped by cell
    int2* eg = (int2*)alloc((size_t)NE * 8);       // c2g edges grouped by gene
    int2* st_c = (int2*)alloc((size_t)NE * 8);     // coarse-bucketed staging
    int2* st_g = (int2*)alloc((size_t)NE * 8);
    int* ccur_c = (int*)alloc(256 * 4);
    int* ccur_g = (int*)alloc(256 * 4);
    unsigned short* Wg0 = (unsigned short*)alloc((size_t)D * KCAT * 2);
    unsigned short* Wc0 = (unsigned short*)alloc((size_t)D * KCAT * 2);
    unsigned short* Wc1 = (unsigned short*)alloc((size_t)D * KCAT * 2);
    float* bg0 = (float*)alloc(D * 4);
    float* bc0 = (float*)alloc(D * 4);
    float* bc1 = (float*)alloc(D * 4);
    int* part_g = (int*)alloc(SCAN_NB * 4);
    int* boff_g = (int*)alloc(SCAN_NB * 4);
    int* part_c = (int*)alloc(SCAN_NB * 4);
    int* boff_c = (int*)alloc(SCAN_NB * 4);

    hipMemsetAsync(cnt_g, 0, NG * 4, stream);
    hipMemsetAsync(cnt_c, 0, NC * 4, stream);

    // cell prep only (gene x conversion now happens inside gene_fused)
    prep_x<<<(NC * 64 + 255) / 256, 256, 0, stream>>>(x_cell, w_cc, Acat_c0 + 256, Acat_c0 + 512, KCAT, NC);

    const int WW = D * D;
    build_wcat<<<(WW + 255) / 256, 256, 0, stream>>>(
        Wrel + 1 * WW, Wroot + 1 * WW, Wroot + 2 * WW, Wrel + 2 * WW,
        brel + 1 * D, brel + 2 * D, Wg0, bg0);
    build_wcat<<<(WW + 255) / 256, 256, 0, stream>>>(
        Wrel + 0 * WW, Wroot + 0 * WW, Wroot + 3 * WW, Wrel + 3 * WW,
        brel + 0 * D, brel + 3 * D, Wc0, bc0);
    build_wcat<<<(WW + 255) / 256, 256, 0, stream>>>(
        Wrel + 4 * WW, Wroot + 4 * WW, Wroot + 7 * WW, Wrel + 7 * WW,
        brel + 4 * D, brel + 7 * D, Wc1, bc1);

    // ---- CSR build ----
    count_edges<<<(NE + CE_CHUNK - 1) / CE_CHUNK, 256, 0, stream>>>(dst_g2c, dst_c2g, cnt_c, cnt_g);
    scan_phaseA<<<2 * SCAN_NB, SCAN_NT, 0, stream>>>(cnt_g, NG, part_g, cnt_c, NC, part_c);
    scan_phaseB<<<2, SCAN_NB, 0, stream>>>(part_g, boff_g, rp_g, NG, part_c, boff_c, rp_c, NC);
    scan_phaseC<<<2 * SCAN_NB, SCAN_NT, 0, stream>>>(cnt_g, NG, boff_g, rp_g, cnt_c, NC, boff_c, rp_c);
    init_coarse<<<1, 256, 0, stream>>>(rp_c, rp_g, ccur_c, ccur_g);
    const int P1B = (NE + P1_CHUNK - 1) / P1_CHUNK;
    bucket_pass1<<<dim3(P1B, 2), 256, 0, stream>>>(
        src_g2c, dst_g2c, w_g2c, ccur_c, st_c,
        src_c2g, dst_c2g, w_c2g, ccur_g, st_g);
    bucket_pass2<<<P2_CBLK + P2_GBLK, 256, 0, stream>>>(st_c, rp_c, ec, st_g, rp_g, eg);
    sort_cell_edges<<<NC, 256, 0, stream>>>(rp_c, ec);

    // ---- fused gene layer (produces xg1 + side bf16 xg0b) ----
    gene_fused<<<(NG + 63) / 64, 256, 0, stream>>>(
        x_gene, w_gg, rp_g, eg, Acat_c0 + 256, KCAT, Wg0, bg0, xg0b, xg1);

    // ---- Layer 0 cells ----
    agg_cell<<<NC, 256, 0, stream>>>(rp_c, ec, xg0b, D, Acat_c0, KCAT);
    gemm_tile<<<dim3((NC + 127) / 128, 2), 256, 0, stream>>>(
        Acat_c0, Wc0, bc0, w_cc, Acat_c1 + 256, KCAT, Acat_c1 + 512, NC);

    // ---- Layer 1 cells ----
    agg_cell<<<NC, 256, 0, stream>>>(rp_c, ec, xg1, D, Acat_c1, KCAT);
    gemm_tile<<<dim3((NC + 127) / 128, 2), 256, 0, stream>>>(
        Acat_c1, Wc1, bc1, nullptr, xc2, D, nullptr, NC);

    // ---- output projection ----
    out_kernel<<<NC / 4, 256, 0, stream>>>(xc2, Wout, bout, out);
}

// Round 7
// 698.530 us; speedup vs baseline: 1.1009x; 1.1009x over previous
//
#include <hip/hip_runtime.h>

// Problem constants
static constexpr int NG   = 100000;
static constexpr int NC   = 2000;
static constexpr int D    = 256;
static constexpr int NE   = 1000000;
static constexpr int NOUTD= 64;
static constexpr int KCAT = 768;          // concatenated K: [agg | x | v]

typedef __bf16 bf16x8 __attribute__((ext_vector_type(8)));
typedef float  f32x4  __attribute__((ext_vector_type(4)));

__device__ __forceinline__ unsigned short f2bf(float f) {
    unsigned u = __float_as_uint(f);
    u += 0x7fffu + ((u >> 16) & 1u);   // RNE
    return (unsigned short)(u >> 16);
}
__device__ __forceinline__ float bflo(unsigned x) { return __uint_as_float((x & 0xffffu) << 16); }
__device__ __forceinline__ float bfhi(unsigned x) { return __uint_as_float(x & 0xffff0000u); }

__device__ __forceinline__ void async16(const void* g, void* l) {
    __builtin_amdgcn_global_load_lds(
        (const __attribute__((address_space(1))) void*)g,
        (__attribute__((address_space(3))) void*)l, 16, 0, 0);
}

// ---------------- prep (cells only): f32 -> bf16 x and v=x*w ----------------
__global__ void prep_x(const float* __restrict__ x, const float* __restrict__ w,
                       unsigned short* __restrict__ dx, unsigned short* __restrict__ dv,
                       long stride, int rows) {
    int i = blockIdx.x * blockDim.x + threadIdx.x;   // one per 4 elements
    if (i >= rows * (D / 4)) return;
    int row = i >> 6, c4 = (i & 63) * 4;
    float4 xv = *reinterpret_cast<const float4*>(x + (size_t)row * D + c4);
    float wv = w[row];
    uint2 ox, ov;
    ox.x = (unsigned)f2bf(xv.x) | ((unsigned)f2bf(xv.y) << 16);
    ox.y = (unsigned)f2bf(xv.z) | ((unsigned)f2bf(xv.w) << 16);
    ov.x = (unsigned)f2bf(xv.x * wv) | ((unsigned)f2bf(xv.y * wv) << 16);
    ov.y = (unsigned)f2bf(xv.z * wv) | ((unsigned)f2bf(xv.w * wv) << 16);
    *reinterpret_cast<uint2*>(dx + (size_t)row * stride + c4) = ox;
    *reinterpret_cast<uint2*>(dv + (size_t)row * stride + c4) = ov;
}

// ---------------- build concatenated bf16 weights [256][768] + bias sums ----
__global__ void build_wcat(const float* __restrict__ Wa,  const float* __restrict__ Wra,
                           const float* __restrict__ Wrb, const float* __restrict__ Wb,
                           const float* __restrict__ ba,  const float* __restrict__ bb,
                           unsigned short* __restrict__ wout, float* __restrict__ bsum) {
    int i = blockIdx.x * blockDim.x + threadIdx.x;
    if (i >= D * D) return;
    int n = i >> 8, k = i & 255;
    wout[(size_t)n * KCAT + k]        = f2bf(Wa[i]);
    wout[(size_t)n * KCAT + 256 + k]  = f2bf(Wra[i] + Wrb[i]);
    wout[(size_t)n * KCAT + 512 + k]  = f2bf(Wb[i]);
    if (i < D) bsum[i] = ba[i] + bb[i];
}

// ---------------- fine counts: LDS-hist for cells, global atomics for genes -
static constexpr int CE_CHUNK = 8192;
__global__ __launch_bounds__(256) void count_edges(const int* __restrict__ dst_g2c,
                                                   const int* __restrict__ dst_c2g,
                                                   int* __restrict__ cnt_c,
                                                   int* __restrict__ cnt_g) {
    __shared__ int h[NC];
    for (int i = threadIdx.x; i < NC; i += 256) h[i] = 0;
    __syncthreads();
    int base = blockIdx.x * CE_CHUNK;
#pragma unroll 4
    for (int t = 0; t < CE_CHUNK / 256; ++t) {
        int e = base + t * 256 + threadIdx.x;
        if (e < NE) {
            atomicAdd(&h[dst_g2c[e]], 1);
            atomicAdd(&cnt_g[dst_c2g[e]], 1);
        }
    }
    __syncthreads();
    for (int i = threadIdx.x; i < NC; i += 256)
        if (h[i]) atomicAdd(&cnt_c[i], h[i]);
}

static constexpr int SCAN_NB = 256;
static constexpr int SCAN_NT = 256;

// fused g+c scans: blocks [0,256) handle (cntA,nA), [256,512) handle (cntB,nB)
__global__ __launch_bounds__(256) void scan_phaseA(const int* __restrict__ cntA, int nA,
                                                   int* __restrict__ partA,
                                                   const int* __restrict__ cntB, int nB,
                                                   int* __restrict__ partB) {
    __shared__ int sd[SCAN_NT];
    const int* cnt; int n; int* partials; int b;
    if (blockIdx.x < SCAN_NB) { cnt = cntA; n = nA; partials = partA; b = blockIdx.x; }
    else { cnt = cntB; n = nB; partials = partB; b = blockIdx.x - SCAN_NB; }
    int chunk = (n + SCAN_NB - 1) / SCAN_NB;
    int ts = (chunk + SCAN_NT - 1) / SCAN_NT;
    int bstart = b * chunk;
    int bend = bstart + chunk; if (bend > n) bend = n;
    int start = bstart + threadIdx.x * ts;
    int end = start + ts; if (end > bend) end = bend;
    int sum = 0;
    for (int j = start; j < end; ++j) sum += cnt[j];
    sd[threadIdx.x] = sum;
    __syncthreads();
    for (int off = SCAN_NT / 2; off > 0; off >>= 1) {
        if (threadIdx.x < off) sd[threadIdx.x] += sd[threadIdx.x + off];
        __syncthreads();
    }
    if (threadIdx.x == 0) partials[b] = sd[0];
}

__global__ __launch_bounds__(256) void scan_phaseB(const int* __restrict__ partA,
                                                   int* __restrict__ boffA,
                                                   int* __restrict__ rpA, int nA,
                                                   const int* __restrict__ partB,
                                                   int* __restrict__ boffB,
                                                   int* __restrict__ rpB, int nB) {
    __shared__ int sd[SCAN_NB];
    const int* partials; int* blockoff; int* rp; int n;
    if (blockIdx.x == 0) { partials = partA; blockoff = boffA; rp = rpA; n = nA; }
    else { partials = partB; blockoff = boffB; rp = rpB; n = nB; }
    int t = threadIdx.x;
    int v = partials[t];
    sd[t] = v;
    __syncthreads();
    for (int off = 1; off < SCAN_NB; off <<= 1) {
        int u = (t >= off) ? sd[t - off] : 0;
        __syncthreads();
        sd[t] += u;
        __syncthreads();
    }
    blockoff[t] = sd[t] - v;
    if (t == SCAN_NB - 1) rp[n] = sd[SCAN_NB - 1];
}

__global__ __launch_bounds__(256) void scan_phaseC(const int* __restrict__ cntA, int nA,
                                                   const int* __restrict__ boffA,
                                                   int* __restrict__ rpA,
                                                   const int* __restrict__ cntB, int nB,
                                                   const int* __restrict__ boffB,
                                                   int* __restrict__ rpB) {
    __shared__ int sd[SCAN_NT];
    const int* cnt; int n; const int* blockoff; int* rp; int b;
    if (blockIdx.x < SCAN_NB) { cnt = cntA; n = nA; blockoff = boffA; rp = rpA; b = blockIdx.x; }
    else { cnt = cntB; n = nB; blockoff = boffB; rp = rpB; b = blockIdx.x - SCAN_NB; }
    int chunk = (n + SCAN_NB - 1) / SCAN_NB;
    int ts = (chunk + SCAN_NT - 1) / SCAN_NT;
    int bstart = b * chunk;
    int bend = bstart + chunk; if (bend > n) bend = n;
    int start = bstart + threadIdx.x * ts;
    int end = start + ts; if (end > bend) end = bend;
    int sum = 0;
    for (int j = start; j < end; ++j) sum += cnt[j];
    sd[threadIdx.x] = sum;
    __syncthreads();
    for (int off = 1; off < SCAN_NT; off <<= 1) {
        int u = (threadIdx.x >= off) ? sd[threadIdx.x - off] : 0;
        __syncthreads();
        sd[threadIdx.x] += u;
        __syncthreads();
    }
    int run = blockoff[b] + sd[threadIdx.x] - sum;
    for (int j = start; j < end; ++j) { rp[j] = run; run += cnt[j]; }
}

// ---------------- two-level binned CSR fill ---------------------------------
__global__ void init_coarse(const int* __restrict__ rp_c, const int* __restrict__ rp_g,
                            int* __restrict__ cc, int* __restrict__ cg) {
    int t = threadIdx.x;
    int ic = t << 3;  if (ic > NC) ic = NC;
    int ig = t << 9;  if (ig > NG) ig = NG;
    cc[t] = rp_c[ic];
    cg[t] = rp_g[ig];
}

// pass1 (fused c/g via blockIdx.y): scatter edges into 256 coarse buckets
static constexpr int P1_CHUNK = 8192;
__global__ __launch_bounds__(256) void bucket_pass1(
        const int* __restrict__ srcA, const int* __restrict__ dstA, const float* __restrict__ wA,
        int* __restrict__ curA, int2* __restrict__ outA,
        const int* __restrict__ srcB, const int* __restrict__ dstB, const float* __restrict__ wB,
        int* __restrict__ curB, int2* __restrict__ outB) {
    __shared__ int hist[256], lcur[256], gbase[256];
    const int* src; const int* dst; const float* w; int* coarse_cur; int2* out;
    int shift, packshift;
    if (blockIdx.y == 0) { src = srcA; dst = dstA; w = wA; coarse_cur = curA; out = outA; shift = 3; packshift = 17; }
    else { src = srcB; dst = dstB; w = wB; coarse_cur = curB; out = outB; shift = 9; packshift = 11; }
    int tid = threadIdx.x;
    hist[tid] = 0;
    __syncthreads();
    int base = blockIdx.x * P1_CHUNK;
    int mybin[P1_CHUNK / 256];
#pragma unroll
    for (int t = 0; t < P1_CHUNK / 256; ++t) {
        int e = base + t * 256 + tid;
        if (e < NE) {
            int b = dst[e] >> shift;
            mybin[t] = b;
            atomicAdd(&hist[b], 1);
        } else mybin[t] = -1;
    }
    __syncthreads();
    int v = hist[tid];
    gbase[tid] = v ? atomicAdd(&coarse_cur[tid], v) : 0;
    lcur[tid] = 0;
    __syncthreads();
#pragma unroll
    for (int t = 0; t < P1_CHUNK / 256; ++t) {
        int b = mybin[t];
        if (b < 0) continue;
        int e = base + t * 256 + tid;
        int pos = gbase[b] + atomicAdd(&lcur[b], 1);
        int dl = dst[e] & ((1 << shift) - 1);
        out[pos] = make_int2(src[e] | (dl << packshift), __float_as_int(w[e]));
    }
}

// pass2 (fused): fine scatter within each bucket; cells = blocks [0,250), genes after
static constexpr int P2_CBLK = NC / 8;                 // 250
static constexpr int P2_GBLK = (NG + 511) / 512;       // 196
__global__ __launch_bounds__(256) void bucket_pass2(
        const int2* __restrict__ stC, const int* __restrict__ rpC, int2* __restrict__ outC,
        const int2* __restrict__ stG, const int* __restrict__ rpG, int2* __restrict__ outG) {
    __shared__ int cur[512];
    const int2* staged; const int* rp; int2* out; int shift, packshift, ndst, b;
    if (blockIdx.x < P2_CBLK) { staged = stC; rp = rpC; out = outC; shift = 3; packshift = 17; ndst = NC; b = blockIdx.x; }
    else { staged = stG; rp = rpG; out = outG; shift = 9; packshift = 11; ndst = NG; b = blockIdx.x - P2_CBLK; }
    int nf = 1 << shift;
    int d0 = b << shift;
    for (int f = threadIdx.x; f < nf; f += 256) {
        int d = d0 + f;
        cur[f] = (d < ndst) ? rp[d] : 0;
    }
    __syncthreads();
    int hi = (b + 1) << shift; if (hi > ndst) hi = ndst;
    int j0 = rp[d0], j1 = rp[hi];
    for (int j = j0 + threadIdx.x; j < j1; j += 256) {
        int2 e = staged[j];
        int f = ((unsigned)e.x) >> packshift;
        int pos = atomicAdd(&cur[f], 1);
        out[pos] = make_int2(e.x & ((1 << packshift) - 1), e.y);
    }
}

// ---------------- per-cell sort of edge segments by src gene ----------------
__global__ __launch_bounds__(256) void sort_cell_edges(const int* __restrict__ rp,
                                                       int2* __restrict__ ec) {
    __shared__ int2 s[1024];
    int c = blockIdx.x;
    int j0 = rp[c], j1 = rp[c + 1];
    int n = j1 - j0;
    if (n <= 1 || n > 1024) return;   // skip = perf-only fallback
    for (int i = threadIdx.x; i < 1024; i += 256)
        s[i] = (i < n) ? ec[j0 + i] : make_int2(0x7fffffff, 0);
    __syncthreads();
    for (int k = 2; k <= 1024; k <<= 1) {
        for (int jj = k >> 1; jj > 0; jj >>= 1) {
#pragma unroll
            for (int t = 0; t < 4; ++t) {
                int i = threadIdx.x + t * 256;
                int ixj = i ^ jj;
                if (ixj > i) {
                    int2 a = s[i], b = s[ixj];
                    bool up = ((i & k) == 0);
                    if ((a.x > b.x) == up) { s[i] = b; s[ixj] = a; }
                }
            }
            __syncthreads();
        }
    }
    for (int i = threadIdx.x; i < n; i += 256) ec[j0 + i] = s[i];
}

// ---------------- gene aggregation: one wave per destination row ------------
// High-occupancy (12 VGPR) latency-bound gather; cell matrix (1 MB) is
// L2-resident. Writes dense [NG][256] bf16.
__global__ void agg_gene(const int* __restrict__ rp, const int2* __restrict__ eg,
                         const unsigned short* __restrict__ src, long sstride,
                         unsigned short* __restrict__ out, long ostride, int nrows) {
    int wave = (blockIdx.x * blockDim.x + threadIdx.x) >> 6;
    int lane = threadIdx.x & 63;
    if (wave >= nrows) return;
    int j0 = rp[wave], j1 = rp[wave + 1];
    float a0 = 0.f, a1 = 0.f, a2 = 0.f, a3 = 0.f;
    int npair = (j1 - j0) & ~1;
    for (int j = j0; j < j0 + npair; j += 2) {
        int2 e1 = eg[j], e2 = eg[j + 1];
        float w1 = __int_as_float(e1.y), w2 = __int_as_float(e2.y);
        uint2 p1 = *reinterpret_cast<const uint2*>(src + (size_t)e1.x * sstride + lane * 4);
        uint2 p2 = *reinterpret_cast<const uint2*>(src + (size_t)e2.x * sstride + lane * 4);
        a0 += w1 * bflo(p1.x) + w2 * bflo(p2.x);
        a1 += w1 * bfhi(p1.x) + w2 * bfhi(p2.x);
        a2 += w1 * bflo(p1.y) + w2 * bflo(p2.y);
        a3 += w1 * bfhi(p1.y) + w2 * bfhi(p2.y);
    }
    if (npair < j1 - j0) {
        int2 e = eg[j0 + npair];
        float w = __int_as_float(e.y);
        uint2 pk = *reinterpret_cast<const uint2*>(src + (size_t)e.x * sstride + lane * 4);
        a0 += w * bflo(pk.x); a1 += w * bfhi(pk.x);
        a2 += w * bflo(pk.y); a3 += w * bfhi(pk.y);
    }
    uint2 o;
    o.x = (unsigned)f2bf(a0) | ((unsigned)f2bf(a1) << 16);
    o.y = (unsigned)f2bf(a2) | ((unsigned)f2bf(a3) << 16);
    *reinterpret_cast<uint2*>(out + (size_t)wave * ostride + lane * 4) = o;
}

// ---------------- gene GEMM: xg1 = relu(agg@W1^T + x@Wc^T + w*(x@W2^T) + b) -
// m97-style 128x128 tile, BK=64. K=512 total: segment A (agg, async16) into
// accA; segment X (x_gene f32, converted in-register, side-writes xg0b bf16)
// into accA (vs Wroot-comb) and accV (vs Wrel2). Epilogue applies per-row
// w_gg to accV: (x*w)@W2^T == w*(x@W2^T) — the v-copy never exists.
__global__ __launch_bounds__(256, 2) void gene_gemm(
        const unsigned short* __restrict__ Agg,  // [NG][256] bf16
        const float* __restrict__ x_gene,        // [NG][256] f32
        const float* __restrict__ w_gg,          // [NG]
        const unsigned short* __restrict__ W,    // [256][768]: rel1|rootc|rel2
        const float* __restrict__ bias,          // [256]
        unsigned short* __restrict__ xg0b,       // side out: bf16 x [NG][256]
        unsigned short* __restrict__ xg1) {      // out [NG][256]
    __shared__ unsigned short As[128 * 64];      // 16 KB
    __shared__ unsigned short Bs1[128 * 64];     // 16 KB
    __shared__ unsigned short Bs2[128 * 64];     // 16 KB
    int tid = threadIdx.x;
    int wv = tid >> 6, ln = tid & 63;
    int lm = ln & 15, lq = ln >> 4;
    int m0 = blockIdx.x * 128;
    int nb = blockIdx.y * 128;
    int m0w = m0 + (wv >> 1) * 64;
    int n0w = nb + (wv & 1) * 64;

    f32x4 accA[4][4], accV[4][4];
#pragma unroll
    for (int i = 0; i < 4; ++i)
#pragma unroll
        for (int j = 0; j < 4; ++j) { accA[i][j] = f32x4{0,0,0,0}; accV[i][j] = f32x4{0,0,0,0}; }

    // ---- segment A: agg @ Wrel1^T ----
    for (int k0 = 0; k0 < 256; k0 += 64) {
#pragma unroll
        for (int t = 0; t < 4; ++t) {
            int ci = t * 256 + tid;
            int r = ci >> 3, s = ci & 7;
            int cg = s ^ (r & 7);
            int row = m0 + r; if (row >= NG) row = NG - 1;
            async16(Agg + (size_t)row * D + k0 + cg * 8, (unsigned char*)As + ci * 16);
            async16(W + (size_t)(nb + r) * KCAT + k0 + cg * 8, (unsigned char*)Bs1 + ci * 16);
        }
        __syncthreads();
#pragma unroll
        for (int kk = 0; kk < 2; ++kk) {
            bf16x8 a[4], b[4];
#pragma unroll
            for (int i = 0; i < 4; ++i) {
                int r = (wv >> 1) * 64 + i * 16 + lm;
                int s = (kk * 4 + lq) ^ (r & 7);
                a[i] = *reinterpret_cast<const bf16x8*>(As + (r * 8 + s) * 8);
            }
#pragma unroll
            for (int j = 0; j < 4; ++j) {
                int r = (wv & 1) * 64 + j * 16 + lm;
                int s = (kk * 4 + lq) ^ (r & 7);
                b[j] = *reinterpret_cast<const bf16x8*>(Bs1 + (r * 8 + s) * 8);
            }
#pragma unroll
            for (int i = 0; i < 4; ++i)
#pragma unroll
                for (int j = 0; j < 4; ++j)
                    accA[i][j] = __builtin_amdgcn_mfma_f32_16x16x32_bf16(a[i], b[j], accA[i][j], 0, 0, 0);
        }
        __syncthreads();
    }

    // ---- segment X: x @ (Wroot1+Wroot2)^T into accA, x @ Wrel2^T into accV -
    for (int k0 = 0; k0 < 256; k0 += 64) {
#pragma unroll
        for (int t = 0; t < 4; ++t) {
            int ci = t * 256 + tid;          // chunk over [128 rows][8 chunks]
            int r = ci >> 3, s = ci & 7;
            int row = m0 + r; if (row >= NG) row = NG - 1;
            const float* xp = x_gene + (size_t)row * D + k0 + s * 8;
            float4 v0 = *reinterpret_cast<const float4*>(xp);
            float4 v1 = *reinterpret_cast<const float4*>(xp + 4);
            uint4 pk;
            pk.x = (unsigned)f2bf(v0.x) | ((unsigned)f2bf(v0.y) << 16);
            pk.y = (unsigned)f2bf(v0.z) | ((unsigned)f2bf(v0.w) << 16);
            pk.z = (unsigned)f2bf(v1.x) | ((unsigned)f2bf(v1.y) << 16);
            pk.w = (unsigned)f2bf(v1.z) | ((unsigned)f2bf(v1.w) << 16);
            *reinterpret_cast<uint4*>(xg0b + (size_t)row * D + k0 + s * 8) = pk;
            int slot = s ^ (r & 7);
            *reinterpret_cast<uint4*>(reinterpret_cast<unsigned char*>(As) + (r * 8 + slot) * 16) = pk;
            async16(W + (size_t)(nb + r) * KCAT + 256 + k0 + s * 8 * 0 + (s ^ (r & 7)) * 0 + ( (s ^ (r & 7)) ? 0 : 0) + ( ( (ci & 7) ^ (r & 7) ) * 8 ),
                    (unsigned char*)Bs1 + ci * 16);
            async16(W + (size_t)(nb + r) * KCAT + 512 + k0 + ((s ^ (r & 7)) * 8),
                    (unsigned char*)Bs2 + ci * 16);
        }
        __syncthreads();
#pragma unroll
        for (int kk = 0; kk < 2; ++kk) {
            bf16x8 a[4], b1[4], b2[4];
#pragma unroll
            for (int i = 0; i < 4; ++i) {
                int r = (wv >> 1) * 64 + i * 16 + lm;
                int s = (kk * 4 + lq) ^ (r & 7);
                a[i] = *reinterpret_cast<const bf16x8*>(As + (r * 8 + s) * 8);
            }
#pragma unroll
            for (int j = 0; j < 4; ++j) {
                int r = (wv & 1) * 64 + j * 16 + lm;
                int s = (kk * 4 + lq) ^ (r & 7);
                b1[j] = *reinterpret_cast<const bf16x8*>(Bs1 + (r * 8 + s) * 8);
                b2[j] = *reinterpret_cast<const bf16x8*>(Bs2 + (r * 8 + s) * 8);
            }
#pragma unroll
            for (int i = 0; i < 4; ++i)
#pragma unroll
                for (int j = 0; j < 4; ++j) {
                    accA[i][j] = __builtin_amdgcn_mfma_f32_16x16x32_bf16(a[i], b1[j], accA[i][j], 0, 0, 0);
                    accV[i][j] = __builtin_amdgcn_mfma_f32_16x16x32_bf16(a[i], b2[j], accV[i][j], 0, 0, 0);
                }
        }
        __syncthreads();
    }

    // ---- epilogue ----
#pragma unroll
    for (int i = 0; i < 4; ++i) {
#pragma unroll
        for (int r4 = 0; r4 < 4; ++r4) {
            int row = m0w + i * 16 + lq * 4 + r4;
            if (row >= NG) continue;
            float wr = w_gg[row];
#pragma unroll
            for (int j = 0; j < 4; ++j) {
                int col = n0w + j * 16 + lm;
                float v = accA[i][j][r4] + wr * accV[i][j][r4] + bias[col];
                v = v > 0.f ? v : 0.f;
                xg1[(size_t)row * D + col] = f2bf(v);
            }
        }
    }
}

// ---------------- cell aggregation: one block per cell, LDS reduce ----------
__global__ __launch_bounds__(256) void agg_cell(const int* __restrict__ rp,
                                                const int2* __restrict__ ec,
                                                const unsigned short* __restrict__ src, long sstride,
                                                unsigned short* __restrict__ out, long ostride) {
    __shared__ float red[4][D];
    int c = blockIdx.x;
    int wv = threadIdx.x >> 6, ln = threadIdx.x & 63;
    int j0 = rp[c], j1 = rp[c + 1];
    float a0 = 0.f, a1 = 0.f, a2 = 0.f, a3 = 0.f;
    int npair = (j1 - j0) & ~7;        // chunks of 8 = 4 waves x 2 edges
    for (int j = j0 + wv * 2; j < j0 + npair; j += 8) {
        int2 e1 = ec[j], e2 = ec[j + 1];
        float w1 = __int_as_float(e1.y), w2 = __int_as_float(e2.y);
        uint2 p1 = *reinterpret_cast<const uint2*>(src + (size_t)e1.x * sstride + ln * 4);
        uint2 p2 = *reinterpret_cast<const uint2*>(src + (size_t)e2.x * sstride + ln * 4);
        a0 += w1 * bflo(p1.x) + w2 * bflo(p2.x);
        a1 += w1 * bfhi(p1.x) + w2 * bfhi(p2.x);
        a2 += w1 * bflo(p1.y) + w2 * bflo(p2.y);
        a3 += w1 * bfhi(p1.y) + w2 * bfhi(p2.y);
    }
    for (int j = j0 + npair + wv; j < j1; j += 4) {
        int2 e = ec[j];
        float w = __int_as_float(e.y);
        uint2 pk = *reinterpret_cast<const uint2*>(src + (size_t)e.x * sstride + ln * 4);
        a0 += w * bflo(pk.x); a1 += w * bfhi(pk.x);
        a2 += w * bflo(pk.y); a3 += w * bfhi(pk.y);
    }
    red[wv][ln * 4 + 0] = a0; red[wv][ln * 4 + 1] = a1;
    red[wv][ln * 4 + 2] = a2; red[wv][ln * 4 + 3] = a3;
    __syncthreads();
    int col = threadIdx.x;
    float s = red[0][col] + red[1][col] + red[2][col] + red[3][col];
    out[(size_t)c * ostride + col] = f2bf(s);
}

// ---------------- m97-style GEMM (cells): relu(A[M,768] @ W^T + bias) -------
__global__ __launch_bounds__(256, 2) void gemm_tile(
        const unsigned short* __restrict__ A,    // [M][768]
        const unsigned short* __restrict__ W,    // [256][768]
        const float* __restrict__ bias,          // [256]
        const float* __restrict__ wrow,          // nullable per-row scale for vout
        unsigned short* __restrict__ xout, long xstride,
        unsigned short* __restrict__ vout,       // nullable, same stride
        int M) {
    __shared__ unsigned short As[128 * 64];
    __shared__ unsigned short Bs[128 * 64];
    int tid = threadIdx.x;
    int wv = tid >> 6, ln = tid & 63;
    int lm = ln & 15, lq = ln >> 4;
    int m0 = blockIdx.x * 128;
    int nb = blockIdx.y * 128;
    int m0w = m0 + (wv >> 1) * 64;
    int n0w = nb + (wv & 1) * 64;

    f32x4 acc[4][4];
#pragma unroll
    for (int i = 0; i < 4; ++i)
#pragma unroll
        for (int j = 0; j < 4; ++j) acc[i][j] = f32x4{0.f, 0.f, 0.f, 0.f};

    for (int k0 = 0; k0 < KCAT; k0 += 64) {
#pragma unroll
        for (int t = 0; t < 4; ++t) {
            int ci = t * 256 + tid;
            int r = ci >> 3, s = ci & 7;
            int cg = s ^ (r & 7);
            int row = m0 + r; if (row >= M) row = M - 1;
            async16(A + (size_t)row * KCAT + k0 + cg * 8,
                    (unsigned char*)As + ci * 16);
        }
#pragma unroll
        for (int t = 0; t < 4; ++t) {
            int ci = t * 256 + tid;
            int r = ci >> 3, s = ci & 7;
            int cg = s ^ (r & 7);
            async16(W + (size_t)(nb + r) * KCAT + k0 + cg * 8,
                    (unsigned char*)Bs + ci * 16);
        }
        __syncthreads();
#pragma unroll
        for (int kk = 0; kk < 2; ++kk) {
            bf16x8 a[4], b[4];
#pragma unroll
            for (int i = 0; i < 4; ++i) {
                int r = (wv >> 1) * 64 + i * 16 + lm;
                int c = kk * 4 + lq;
                int s = c ^ (r & 7);
                a[i] = *reinterpret_cast<const bf16x8*>(As + (r * 8 + s) * 8);
            }
#pragma unroll
            for (int j = 0; j < 4; ++j) {
                int r = (wv & 1) * 64 + j * 16 + lm;
                int c = kk * 4 + lq;
                int s = c ^ (r & 7);
                b[j] = *reinterpret_cast<const bf16x8*>(Bs + (r * 8 + s) * 8);
            }
#pragma unroll
            for (int i = 0; i < 4; ++i)
#pragma unroll
                for (int j = 0; j < 4; ++j)
                    acc[i][j] = __builtin_amdgcn_mfma_f32_16x16x32_bf16(a[i], b[j], acc[i][j], 0, 0, 0);
        }
        __syncthreads();
    }

#pragma unroll
    for (int i = 0; i < 4; ++i) {
#pragma unroll
        for (int r4 = 0; r4 < 4; ++r4) {
            int rr = m0w + i * 16 + lq * 4 + r4;
            if (rr >= M) continue;
            float wr = wrow ? wrow[rr] : 0.f;
#pragma unroll
            for (int j = 0; j < 4; ++j) {
                int col = n0w + j * 16 + lm;
                float v = acc[i][j][r4] + bias[col];
                v = v > 0.f ? v : 0.f;
                xout[(size_t)rr * xstride + col] = f2bf(v);
                if (vout) vout[(size_t)rr * xstride + col] = f2bf(v * wr);
            }
        }
    }
}

// ---------------- final projection: out = xc2 @ Wout^T + bout (fp32) --------
__global__ void out_kernel(const unsigned short* __restrict__ xc, const float* __restrict__ Wout,
                           const float* __restrict__ bout, float* __restrict__ out) {
    __shared__ float srow[4][D];
    int r = threadIdx.x >> 6;
    int o = threadIdx.x & 63;
    int c = blockIdx.x * 4 + r;
    for (int t = threadIdx.x; t < 4 * D; t += 256) {
        int rr = blockIdx.x * 4 + (t >> 8);
        unsigned short h = xc[(size_t)rr * D + (t & 255)];
        srow[t >> 8][t & 255] = __uint_as_float(((unsigned)h) << 16);
    }
    __syncthreads();
    float s = 0.f;
    const float* wo = Wout + o * D;
    for (int k = 0; k < D; ++k) s += srow[r][k] * wo[k];
    out[(size_t)c * NOUTD + o] = s + bout[o];
}

// ---------------- orchestration ---------------------------------------------
extern "C" void kernel_launch(void* const* d_in, const int* in_sizes, int n_in,
                              void* d_out, int out_size, void* d_ws, size_t ws_size,
                              hipStream_t stream) {
    const float* x_gene = (const float*)d_in[0];
    const float* x_cell = (const float*)d_in[1];
    const int*   src_g2c = (const int*)d_in[2];
    const int*   dst_g2c = (const int*)d_in[3];
    const int*   src_c2g = (const int*)d_in[4];
    const int*   dst_c2g = (const int*)d_in[5];
    const float* w_g2c = (const float*)d_in[8];
    const float* w_c2g = (const float*)d_in[9];
    const float* w_gg  = (const float*)d_in[10];
    const float* w_cc  = (const float*)d_in[11];
    const float* Wrel  = (const float*)d_in[12];
    const float* brel  = (const float*)d_in[13];
    const float* Wroot = (const float*)d_in[14];
    const float* Wout  = (const float*)d_in[15];
    const float* bout  = (const float*)d_in[16];
    float* out = (float*)d_out;

    char* p = (char*)d_ws;
    auto alloc = [&](size_t bytes) -> char* {
        char* r = p;
        p += (bytes + 255) & ~(size_t)255;
        return r;
    };

    unsigned short* xg0b    = (unsigned short*)alloc((size_t)NG * D * 2);
    unsigned short* xg1     = (unsigned short*)alloc((size_t)NG * D * 2);
    unsigned short* agg_g   = (unsigned short*)alloc((size_t)NG * D * 2);
    unsigned short* Acat_c0 = (unsigned short*)alloc((size_t)NC * KCAT * 2);
    unsigned short* Acat_c1 = (unsigned short*)alloc((size_t)NC * KCAT * 2);
    unsigned short* xc2     = (unsigned short*)alloc((size_t)NC * D * 2);
    int* rp_g  = (int*)alloc((NG + 1) * 4);
    int* cnt_g = (int*)alloc(NG * 4);
    int* rp_c  = (int*)alloc((NC + 1) * 4);
    int* cnt_c = (int*)alloc(NC * 4);
    int2* ec = (int2*)alloc((size_t)NE * 8);       // g2c edges grouped by cell
    int2* eg = (int2*)alloc((size_t)NE * 8);       // c2g edges grouped by gene
    int2* st_c = (int2*)alloc((size_t)NE * 8);     // coarse-bucketed staging
    int2* st_g = (int2*)alloc((size_t)NE * 8);
    int* ccur_c = (int*)alloc(256 * 4);
    int* ccur_g = (int*)alloc(256 * 4);
    unsigned short* Wg0 = (unsigned short*)alloc((size_t)D * KCAT * 2);
    unsigned short* Wc0 = (unsigned short*)alloc((size_t)D * KCAT * 2);
    unsigned short* Wc1 = (unsigned short*)alloc((size_t)D * KCAT * 2);
    float* bg0 = (float*)alloc(D * 4);
    float* bc0 = (float*)alloc(D * 4);
    float* bc1 = (float*)alloc(D * 4);
    int* part_g = (int*)alloc(SCAN_NB * 4);
    int* boff_g = (int*)alloc(SCAN_NB * 4);
    int* part_c = (int*)alloc(SCAN_NB * 4);
    int* boff_c = (int*)alloc(SCAN_NB * 4);

    hipMemsetAsync(cnt_g, 0, NG * 4, stream);
    hipMemsetAsync(cnt_c, 0, NC * 4, stream);

    // cell prep only (gene x conversion happens inside gene_gemm)
    prep_x<<<(NC * 64 + 255) / 256, 256, 0, stream>>>(x_cell, w_cc, Acat_c0 + 256, Acat_c0 + 512, KCAT, NC);

    const int WW = D * D;
    build_wcat<<<(WW + 255) / 256, 256, 0, stream>>>(
        Wrel + 1 * WW, Wroot + 1 * WW, Wroot + 2 * WW, Wrel + 2 * WW,
        brel + 1 * D, brel + 2 * D, Wg0, bg0);
    build_wcat<<<(WW + 255) / 256, 256, 0, stream>>>(
        Wrel + 0 * WW, Wroot + 0 * WW, Wroot + 3 * WW, Wrel + 3 * WW,
        brel + 0 * D, brel + 3 * D, Wc0, bc0);
    build_wcat<<<(WW + 255) / 256, 256, 0, stream>>>(
        Wrel + 4 * WW, Wroot + 4 * WW, Wroot + 7 * WW, Wrel + 7 * WW,
        brel + 4 * D, brel + 7 * D, Wc1, bc1);

    // ---- CSR build ----
    count_edges<<<(NE + CE_CHUNK - 1) / CE_CHUNK, 256, 0, stream>>>(dst_g2c, dst_c2g, cnt_c, cnt_g);
    scan_phaseA<<<2 * SCAN_NB, SCAN_NT, 0, stream>>>(cnt_g, NG, part_g, cnt_c, NC, part_c);
    scan_phaseB<<<2, SCAN_NB, 0, stream>>>(part_g, boff_g, rp_g, NG, part_c, boff_c, rp_c, NC);
    scan_phaseC<<<2 * SCAN_NB, SCAN_NT, 0, stream>>>(cnt_g, NG, boff_g, rp_g, cnt_c, NC, boff_c, rp_c);
    init_coarse<<<1, 256, 0, stream>>>(rp_c, rp_g, ccur_c, ccur_g);
    const int P1B = (NE + P1_CHUNK - 1) / P1_CHUNK;
    bucket_pass1<<<dim3(P1B, 2), 256, 0, stream>>>(
        src_g2c, dst_g2c, w_g2c, ccur_c, st_c,
        src_c2g, dst_c2g, w_c2g, ccur_g, st_g);
    bucket_pass2<<<P2_CBLK + P2_GBLK, 256, 0, stream>>>(st_c, rp_c, ec, st_g, rp_g, eg);
    sort_cell_edges<<<NC, 256, 0, stream>>>(rp_c, ec);

    // ---- gene path: high-occupancy gather, then fused-convert GEMM ----
    agg_gene<<<(NG + 3) / 4, 256, 0, stream>>>(rp_g, eg, Acat_c0 + 256, KCAT, agg_g, D, NG);
    gene_gemm<<<dim3((NG + 127) / 128, 2), 256, 0, stream>>>(
        agg_g, x_gene, w_gg, Wg0, bg0, xg0b, xg1);

    // ---- Layer 0 cells ----
    agg_cell<<<NC, 256, 0, stream>>>(rp_c, ec, xg0b, D, Acat_c0, KCAT);
    gemm_tile<<<dim3((NC + 127) / 128, 2), 256, 0, stream>>>(
        Acat_c0, Wc0, bc0, w_cc, Acat_c1 + 256, KCAT, Acat_c1 + 512, NC);

    // ---- Layer 1 cells ----
    agg_cell<<<NC, 256, 0, stream>>>(rp_c, ec, xg1, D, Acat_c1, KCAT);
    gemm_tile<<<dim3((NC + 127) / 128, 2), 256, 0, stream>>>(
        Acat_c1, Wc1, bc1, nullptr, xc2, D, nullptr, NC);

    // ---- output projection ----
    out_kernel<<<NC / 4, 256, 0, stream>>>(xc2, Wout, bout, out);
}

// Round 8
// 660.696 us; speedup vs baseline: 1.1640x; 1.0573x over previous
//
#include <hip/hip_runtime.h>

// Problem constants
static constexpr int NG   = 100000;
static constexpr int NC   = 2000;
static constexpr int D    = 256;
static constexpr int NE   = 1000000;
static constexpr int NOUTD= 64;
static constexpr int KCAT = 768;          // concatenated K: [agg | x | v]

typedef __bf16 bf16x8 __attribute__((ext_vector_type(8)));
typedef float  f32x4  __attribute__((ext_vector_type(4)));

__device__ __forceinline__ unsigned short f2bf(float f) {
    unsigned u = __float_as_uint(f);
    u += 0x7fffu + ((u >> 16) & 1u);   // RNE
    return (unsigned short)(u >> 16);
}
__device__ __forceinline__ float bflo(unsigned x) { return __uint_as_float((x & 0xffffu) << 16); }
__device__ __forceinline__ float bfhi(unsigned x) { return __uint_as_float(x & 0xffff0000u); }

__device__ __forceinline__ void async16(const void* g, void* l) {
    __builtin_amdgcn_global_load_lds(
        (const __attribute__((address_space(1))) void*)g,
        (__attribute__((address_space(3))) void*)l, 16, 0, 0);
}

// ---------------- prep (cells only): f32 -> bf16 x and v=x*w ----------------
__global__ void prep_x(const float* __restrict__ x, const float* __restrict__ w,
                       unsigned short* __restrict__ dx, unsigned short* __restrict__ dv,
                       long stride, int rows) {
    int i = blockIdx.x * blockDim.x + threadIdx.x;   // one per 4 elements
    if (i >= rows * (D / 4)) return;
    int row = i >> 6, c4 = (i & 63) * 4;
    float4 xv = *reinterpret_cast<const float4*>(x + (size_t)row * D + c4);
    float wv = w[row];
    uint2 ox, ov;
    ox.x = (unsigned)f2bf(xv.x) | ((unsigned)f2bf(xv.y) << 16);
    ox.y = (unsigned)f2bf(xv.z) | ((unsigned)f2bf(xv.w) << 16);
    ov.x = (unsigned)f2bf(xv.x * wv) | ((unsigned)f2bf(xv.y * wv) << 16);
    ov.y = (unsigned)f2bf(xv.z * wv) | ((unsigned)f2bf(xv.w * wv) << 16);
    *reinterpret_cast<uint2*>(dx + (size_t)row * stride + c4) = ox;
    *reinterpret_cast<uint2*>(dv + (size_t)row * stride + c4) = ov;
}

// -------- build all 3 concatenated bf16 weight mats [256][768] + bias sums --
// y=0: gene L0 (ia=1, ib=2); y=1: cell L0 (0,3); y=2: cell L1 (4,7)
__global__ void build_wcat3(const float* __restrict__ Wrel, const float* __restrict__ Wroot,
                            const float* __restrict__ brel,
                            unsigned short* __restrict__ Wg0, unsigned short* __restrict__ Wc0,
                            unsigned short* __restrict__ Wc1,
                            float* __restrict__ bg0, float* __restrict__ bc0,
                            float* __restrict__ bc1) {
    int i = blockIdx.x * blockDim.x + threadIdx.x;
    if (i >= D * D) return;
    int ia, ib; unsigned short* wout; float* bsum;
    if (blockIdx.y == 0)      { ia = 1; ib = 2; wout = Wg0; bsum = bg0; }
    else if (blockIdx.y == 1) { ia = 0; ib = 3; wout = Wc0; bsum = bc0; }
    else                      { ia = 4; ib = 7; wout = Wc1; bsum = bc1; }
    const int WW = D * D;
    int n = i >> 8, k = i & 255;
    wout[(size_t)n * KCAT + k]        = f2bf(Wrel[ia * WW + i]);
    wout[(size_t)n * KCAT + 256 + k]  = f2bf(Wroot[ia * WW + i] + Wroot[ib * WW + i]);
    wout[(size_t)n * KCAT + 512 + k]  = f2bf(Wrel[ib * WW + i]);
    if (i < D) bsum[i] = brel[ia * D + i] + brel[ib * D + i];
}

// ---------------- coarse histogram: 256 bins per relation -------------------
static constexpr int CC_CHUNK = 8192;
__global__ __launch_bounds__(256) void coarse_count(const int* __restrict__ dst_g2c,
                                                    const int* __restrict__ dst_c2g,
                                                    int* __restrict__ hist) {  // [512]
    __shared__ int h[512];
    h[threadIdx.x] = 0; h[256 + threadIdx.x] = 0;
    __syncthreads();
    int base = blockIdx.x * CC_CHUNK;
#pragma unroll 4
    for (int t = 0; t < CC_CHUNK / 256; ++t) {
        int e = base + t * 256 + threadIdx.x;
        if (e < NE) {
            atomicAdd(&h[dst_g2c[e] >> 3], 1);          // cell bins
            atomicAdd(&h[256 + (dst_c2g[e] >> 9)], 1);  // gene bins
        }
    }
    __syncthreads();
    if (h[threadIdx.x]) atomicAdd(&hist[threadIdx.x], h[threadIdx.x]);
    if (h[256 + threadIdx.x]) atomicAdd(&hist[256 + threadIdx.x], h[256 + threadIdx.x]);
}

// ---- coarse scan: cbase[0..256]=cells, cbase[257..513]=genes; init cursors -
__global__ __launch_bounds__(256) void coarse_scan(const int* __restrict__ hist,
                                                   int* __restrict__ cbase,
                                                   int* __restrict__ ccur_c, int* __restrict__ ccur_g,
                                                   int* __restrict__ rp_c, int* __restrict__ rp_g) {
    __shared__ int sd[256];
    int t = threadIdx.x;
    {
        int v = hist[t];
        sd[t] = v; __syncthreads();
        for (int off = 1; off < 256; off <<= 1) {
            int u = (t >= off) ? sd[t - off] : 0; __syncthreads();
            sd[t] += u; __syncthreads();
        }
        int e = sd[t] - v;
        cbase[t] = e; ccur_c[t] = e;
        if (t == 255) cbase[256] = sd[255];
        __syncthreads();
    }
    {
        int v = hist[256 + t];
        sd[t] = v; __syncthreads();
        for (int off = 1; off < 256; off <<= 1) {
            int u = (t >= off) ? sd[t - off] : 0; __syncthreads();
            sd[t] += u; __syncthreads();
        }
        int e = sd[t] - v;
        cbase[257 + t] = e; ccur_g[t] = e;
        if (t == 255) cbase[513] = sd[255];
    }
    if (t == 0) { rp_c[NC] = NE; rp_g[NG] = NE; }
}

// pass1 (fused c/g via blockIdx.y): scatter edges into 256 coarse buckets
static constexpr int P1_CHUNK = 8192;
__global__ __launch_bounds__(256) void bucket_pass1(
        const int* __restrict__ srcA, const int* __restrict__ dstA, const float* __restrict__ wA,
        int* __restrict__ curA, int2* __restrict__ outA,
        const int* __restrict__ srcB, const int* __restrict__ dstB, const float* __restrict__ wB,
        int* __restrict__ curB, int2* __restrict__ outB) {
    __shared__ int hist[256], lcur[256], gbase[256];
    const int* src; const int* dst; const float* w; int* coarse_cur; int2* out;
    int shift, packshift;
    if (blockIdx.y == 0) { src = srcA; dst = dstA; w = wA; coarse_cur = curA; out = outA; shift = 3; packshift = 17; }
    else { src = srcB; dst = dstB; w = wB; coarse_cur = curB; out = outB; shift = 9; packshift = 11; }
    int tid = threadIdx.x;
    hist[tid] = 0;
    __syncthreads();
    int base = blockIdx.x * P1_CHUNK;
    int mybin[P1_CHUNK / 256];
#pragma unroll
    for (int t = 0; t < P1_CHUNK / 256; ++t) {
        int e = base + t * 256 + tid;
        if (e < NE) {
            int b = dst[e] >> shift;
            mybin[t] = b;
            atomicAdd(&hist[b], 1);
        } else mybin[t] = -1;
    }
    __syncthreads();
    int v = hist[tid];
    gbase[tid] = v ? atomicAdd(&coarse_cur[tid], v) : 0;
    lcur[tid] = 0;
    __syncthreads();
#pragma unroll
    for (int t = 0; t < P1_CHUNK / 256; ++t) {
        int b = mybin[t];
        if (b < 0) continue;
        int e = base + t * 256 + tid;
        int pos = gbase[b] + atomicAdd(&lcur[b], 1);
        int dl = dst[e] & ((1 << shift) - 1);
        out[pos] = make_int2(src[e] | (dl << packshift), __float_as_int(w[e]));
    }
}

// pass2 (fused): per bucket — fine LDS histogram + scan emits rp, then scatter
static constexpr int P2_CBLK = NC / 8;                 // 250
static constexpr int P2_GBLK = (NG + 511) / 512;       // 196
__global__ __launch_bounds__(256) void bucket_pass2(
        const int2* __restrict__ stC, int2* __restrict__ outC, int* __restrict__ rpC,
        const int2* __restrict__ stG, int2* __restrict__ outG, int* __restrict__ rpG,
        const int* __restrict__ cbase) {
    __shared__ int hist[512], cur[512], sd[256];
    const int2* staged; int2* out; int* rp; const int* cb;
    int shift, packshift, ndst, b;
    if (blockIdx.x < P2_CBLK) {
        staged = stC; out = outC; rp = rpC; cb = cbase;
        shift = 3; packshift = 17; ndst = NC; b = blockIdx.x;
    } else {
        staged = stG; out = outG; rp = rpG; cb = cbase + 257;
        shift = 9; packshift = 11; ndst = NG; b = blockIdx.x - P2_CBLK;
    }
    int tid = threadIdx.x;
    int nf = 1 << shift;
    int d0 = b << shift;
    int j0 = cb[b], j1 = cb[b + 1];
    for (int f = tid; f < nf; f += 256) hist[f] = 0;
    __syncthreads();
    for (int j = j0 + tid; j < j1; j += 256)
        atomicAdd(&hist[((unsigned)staged[j].x) >> packshift], 1);
    __syncthreads();
    // exclusive scan over hist[0..nf)
    int chunk = (nf + 255) >> 8;                 // 1 or 2
    int s = 0;
#pragma unroll 2
    for (int k = 0; k < chunk; ++k) {
        int idx = tid * chunk + k;
        if (idx < nf) s += hist[idx];
    }
    sd[tid] = s; __syncthreads();
    for (int off = 1; off < 256; off <<= 1) {
        int u = (tid >= off) ? sd[tid - off] : 0; __syncthreads();
        sd[tid] += u; __syncthreads();
    }
    int run = sd[tid] - s;                       // exclusive base for this thread's chunk
#pragma unroll 2
    for (int k = 0; k < chunk; ++k) {
        int idx = tid * chunk + k;
        if (idx < nf) {
            int h = hist[idx];
            int pos = j0 + run;
            cur[idx] = pos;
            int d = d0 + idx;
            if (d < ndst) rp[d] = pos;
            run += h;
        }
    }
    __syncthreads();
    // scatter within the bucket's contiguous (cache-local) output region
    for (int j = j0 + tid; j < j1; j += 256) {
        int2 e = staged[j];
        int f = ((unsigned)e.x) >> packshift;
        int pos = atomicAdd(&cur[f], 1);
        out[pos] = make_int2(e.x & ((1 << packshift) - 1), e.y);
    }
}

// ---------------- per-cell sort of edge segments by src gene ----------------
__global__ __launch_bounds__(256) void sort_cell_edges(const int* __restrict__ rp,
                                                       int2* __restrict__ ec) {
    __shared__ int2 s[1024];
    int c = blockIdx.x;
    int j0 = rp[c], j1 = rp[c + 1];
    int n = j1 - j0;
    if (n <= 1 || n > 1024) return;   // skip = perf-only fallback
    for (int i = threadIdx.x; i < 1024; i += 256)
        s[i] = (i < n) ? ec[j0 + i] : make_int2(0x7fffffff, 0);
    __syncthreads();
    for (int k = 2; k <= 1024; k <<= 1) {
        for (int jj = k >> 1; jj > 0; jj >>= 1) {
#pragma unroll
            for (int t = 0; t < 4; ++t) {
                int i = threadIdx.x + t * 256;
                int ixj = i ^ jj;
                if (ixj > i) {
                    int2 a = s[i], b = s[ixj];
                    bool up = ((i & k) == 0);
                    if ((a.x > b.x) == up) { s[i] = b; s[ixj] = a; }
                }
            }
            __syncthreads();
        }
    }
    for (int i = threadIdx.x; i < n; i += 256) ec[j0 + i] = s[i];
}

// ------- gene aggregation + x conversion: one wave per destination row ------
// Latency-bound gather (cell matrix L2-resident) with spare BW: the coalesced
// f32->bf16 conversion of x_gene rides along for ~free.
__global__ void agg_gene_conv(const int* __restrict__ rp, const int2* __restrict__ eg,
                              const unsigned short* __restrict__ src, long sstride,
                              const float* __restrict__ x_gene,
                              unsigned short* __restrict__ xg0b,
                              unsigned short* __restrict__ agg_out, int nrows) {
    int wave = (blockIdx.x * blockDim.x + threadIdx.x) >> 6;
    int lane = threadIdx.x & 63;
    if (wave >= nrows) return;
    // convert this row's x to bf16 (coalesced float4 per lane)
    float4 xv = *reinterpret_cast<const float4*>(x_gene + (size_t)wave * D + lane * 4);
    uint2 xo;
    xo.x = (unsigned)f2bf(xv.x) | ((unsigned)f2bf(xv.y) << 16);
    xo.y = (unsigned)f2bf(xv.z) | ((unsigned)f2bf(xv.w) << 16);
    *reinterpret_cast<uint2*>(xg0b + (size_t)wave * D + lane * 4) = xo;
    // gather-aggregate
    int j0 = rp[wave], j1 = rp[wave + 1];
    float a0 = 0.f, a1 = 0.f, a2 = 0.f, a3 = 0.f;
    int npair = (j1 - j0) & ~1;
    for (int j = j0; j < j0 + npair; j += 2) {
        int2 e1 = eg[j], e2 = eg[j + 1];
        float w1 = __int_as_float(e1.y), w2 = __int_as_float(e2.y);
        uint2 p1 = *reinterpret_cast<const uint2*>(src + (size_t)e1.x * sstride + lane * 4);
        uint2 p2 = *reinterpret_cast<const uint2*>(src + (size_t)e2.x * sstride + lane * 4);
        a0 += w1 * bflo(p1.x) + w2 * bflo(p2.x);
        a1 += w1 * bfhi(p1.x) + w2 * bfhi(p2.x);
        a2 += w1 * bflo(p1.y) + w2 * bflo(p2.y);
        a3 += w1 * bfhi(p1.y) + w2 * bfhi(p2.y);
    }
    if (npair < j1 - j0) {
        int2 e = eg[j0 + npair];
        float w = __int_as_float(e.y);
        uint2 pk = *reinterpret_cast<const uint2*>(src + (size_t)e.x * sstride + lane * 4);
        a0 += w * bflo(pk.x); a1 += w * bfhi(pk.x);
        a2 += w * bflo(pk.y); a3 += w * bfhi(pk.y);
    }
    uint2 o;
    o.x = (unsigned)f2bf(a0) | ((unsigned)f2bf(a1) << 16);
    o.y = (unsigned)f2bf(a2) | ((unsigned)f2bf(a3) << 16);
    *reinterpret_cast<uint2*>(agg_out + (size_t)wave * D + lane * 4) = o;
}

// ---------------- gene GEMM: xg1 = relu(agg@W1^T + x@Wc^T + w*(x@W2^T) + b) -
// Pure async16-staged m97 structure, K=512 over two dense bf16 A arrays.
// Segment X does two matmuls per A tile (accA vs Wroot-comb, accV vs Wrel2);
// epilogue applies per-row w_gg to accV.
__global__ __launch_bounds__(256, 2) void gene_gemm(
        const unsigned short* __restrict__ Agg,  // [NG][256] bf16
        const unsigned short* __restrict__ Xb,   // [NG][256] bf16
        const float* __restrict__ w_gg,          // [NG]
        const unsigned short* __restrict__ W,    // [256][768]: rel1|rootc|rel2
        const float* __restrict__ bias,          // [256]
        unsigned short* __restrict__ xg1) {      // out [NG][256]
    __shared__ unsigned short As[128 * 64];      // 16 KB
    __shared__ unsigned short Bs1[128 * 64];     // 16 KB
    __shared__ unsigned short Bs2[128 * 64];     // 16 KB
    int tid = threadIdx.x;
    int wv = tid >> 6, ln = tid & 63;
    int lm = ln & 15, lq = ln >> 4;
    int m0 = blockIdx.x * 128;
    int nb = blockIdx.y * 128;
    int m0w = m0 + (wv >> 1) * 64;
    int n0w = nb + (wv & 1) * 64;

    f32x4 accA[4][4], accV[4][4];
#pragma unroll
    for (int i = 0; i < 4; ++i)
#pragma unroll
        for (int j = 0; j < 4; ++j) { accA[i][j] = f32x4{0,0,0,0}; accV[i][j] = f32x4{0,0,0,0}; }

    // ---- segment A: agg @ Wrel1^T ----
    for (int k0 = 0; k0 < 256; k0 += 64) {
#pragma unroll
        for (int t = 0; t < 4; ++t) {
            int ci = t * 256 + tid;
            int r = ci >> 3, s = ci & 7;
            int cg = s ^ (r & 7);
            int row = m0 + r; if (row >= NG) row = NG - 1;
            async16(Agg + (size_t)row * D + k0 + cg * 8, (unsigned char*)As + ci * 16);
            async16(W + (size_t)(nb + r) * KCAT + k0 + cg * 8, (unsigned char*)Bs1 + ci * 16);
        }
        __syncthreads();
#pragma unroll
        for (int kk = 0; kk < 2; ++kk) {
            bf16x8 a[4], b[4];
#pragma unroll
            for (int i = 0; i < 4; ++i) {
                int r = (wv >> 1) * 64 + i * 16 + lm;
                int s = (kk * 4 + lq) ^ (r & 7);
                a[i] = *reinterpret_cast<const bf16x8*>(As + (r * 8 + s) * 8);
            }
#pragma unroll
            for (int j = 0; j < 4; ++j) {
                int r = (wv & 1) * 64 + j * 16 + lm;
                int s = (kk * 4 + lq) ^ (r & 7);
                b[j] = *reinterpret_cast<const bf16x8*>(Bs1 + (r * 8 + s) * 8);
            }
#pragma unroll
            for (int i = 0; i < 4; ++i)
#pragma unroll
                for (int j = 0; j < 4; ++j)
                    accA[i][j] = __builtin_amdgcn_mfma_f32_16x16x32_bf16(a[i], b[j], accA[i][j], 0, 0, 0);
        }
        __syncthreads();
    }

    // ---- segment X: x @ (Wroot1+Wroot2)^T into accA, x @ Wrel2^T into accV -
    for (int k0 = 0; k0 < 256; k0 += 64) {
#pragma unroll
        for (int t = 0; t < 4; ++t) {
            int ci = t * 256 + tid;
            int r = ci >> 3, s = ci & 7;
            int cg = s ^ (r & 7);
            int row = m0 + r; if (row >= NG) row = NG - 1;
            async16(Xb + (size_t)row * D + k0 + cg * 8, (unsigned char*)As + ci * 16);
            async16(W + (size_t)(nb + r) * KCAT + 256 + k0 + cg * 8, (unsigned char*)Bs1 + ci * 16);
            async16(W + (size_t)(nb + r) * KCAT + 512 + k0 + cg * 8, (unsigned char*)Bs2 + ci * 16);
        }
        __syncthreads();
#pragma unroll
        for (int kk = 0; kk < 2; ++kk) {
            bf16x8 a[4], b1[4], b2[4];
#pragma unroll
            for (int i = 0; i < 4; ++i) {
                int r = (wv >> 1) * 64 + i * 16 + lm;
                int s = (kk * 4 + lq) ^ (r & 7);
                a[i] = *reinterpret_cast<const bf16x8*>(As + (r * 8 + s) * 8);
            }
#pragma unroll
            for (int j = 0; j < 4; ++j) {
                int r = (wv & 1) * 64 + j * 16 + lm;
                int s = (kk * 4 + lq) ^ (r & 7);
                b1[j] = *reinterpret_cast<const bf16x8*>(Bs1 + (r * 8 + s) * 8);
                b2[j] = *reinterpret_cast<const bf16x8*>(Bs2 + (r * 8 + s) * 8);
            }
#pragma unroll
            for (int i = 0; i < 4; ++i)
#pragma unroll
                for (int j = 0; j < 4; ++j) {
                    accA[i][j] = __builtin_amdgcn_mfma_f32_16x16x32_bf16(a[i], b1[j], accA[i][j], 0, 0, 0);
                    accV[i][j] = __builtin_amdgcn_mfma_f32_16x16x32_bf16(a[i], b2[j], accV[i][j], 0, 0, 0);
                }
        }
        __syncthreads();
    }

    // ---- epilogue ----
#pragma unroll
    for (int i = 0; i < 4; ++i) {
#pragma unroll
        for (int r4 = 0; r4 < 4; ++r4) {
            int row = m0w + i * 16 + lq * 4 + r4;
            if (row >= NG) continue;
            float wr = w_gg[row];
#pragma unroll
            for (int j = 0; j < 4; ++j) {
                int col = n0w + j * 16 + lm;
                float v = accA[i][j][r4] + wr * accV[i][j][r4] + bias[col];
                v = v > 0.f ? v : 0.f;
                xg1[(size_t)row * D + col] = f2bf(v);
            }
        }
    }
}

// ---------------- cell aggregation: one block per cell, LDS reduce ----------
__global__ __launch_bounds__(256) void agg_cell(const int* __restrict__ rp,
                                                const int2* __restrict__ ec,
                                                const unsigned short* __restrict__ src, long sstride,
                                                unsigned short* __restrict__ out, long ostride) {
    __shared__ float red[4][D];
    int c = blockIdx.x;
    int wv = threadIdx.x >> 6, ln = threadIdx.x & 63;
    int j0 = rp[c], j1 = rp[c + 1];
    float a0 = 0.f, a1 = 0.f, a2 = 0.f, a3 = 0.f;
    int npair = (j1 - j0) & ~7;        // chunks of 8 = 4 waves x 2 edges
    for (int j = j0 + wv * 2; j < j0 + npair; j += 8) {
        int2 e1 = ec[j], e2 = ec[j + 1];
        float w1 = __int_as_float(e1.y), w2 = __int_as_float(e2.y);
        uint2 p1 = *reinterpret_cast<const uint2*>(src + (size_t)e1.x * sstride + ln * 4);
        uint2 p2 = *reinterpret_cast<const uint2*>(src + (size_t)e2.x * sstride + ln * 4);
        a0 += w1 * bflo(p1.x) + w2 * bflo(p2.x);
        a1 += w1 * bfhi(p1.x) + w2 * bfhi(p2.x);
        a2 += w1 * bflo(p1.y) + w2 * bflo(p2.y);
        a3 += w1 * bfhi(p1.y) + w2 * bfhi(p2.y);
    }
    for (int j = j0 + npair + wv; j < j1; j += 4) {
        int2 e = ec[j];
        float w = __int_as_float(e.y);
        uint2 pk = *reinterpret_cast<const uint2*>(src + (size_t)e.x * sstride + ln * 4);
        a0 += w * bflo(pk.x); a1 += w * bfhi(pk.x);
        a2 += w * bflo(pk.y); a3 += w * bfhi(pk.y);
    }
    red[wv][ln * 4 + 0] = a0; red[wv][ln * 4 + 1] = a1;
    red[wv][ln * 4 + 2] = a2; red[wv][ln * 4 + 3] = a3;
    __syncthreads();
    int col = threadIdx.x;
    float s = red[0][col] + red[1][col] + red[2][col] + red[3][col];
    out[(size_t)c * ostride + col] = f2bf(s);
}

// ---------------- m97-style GEMM (cells): relu(A[M,768] @ W^T + bias) -------
__global__ __launch_bounds__(256, 2) void gemm_tile(
        const unsigned short* __restrict__ A,    // [M][768]
        const unsigned short* __restrict__ W,    // [256][768]
        const float* __restrict__ bias,          // [256]
        const float* __restrict__ wrow,          // nullable per-row scale for vout
        unsigned short* __restrict__ xout, long xstride,
        unsigned short* __restrict__ vout,       // nullable, same stride
        int M) {
    __shared__ unsigned short As[128 * 64];
    __shared__ unsigned short Bs[128 * 64];
    int tid = threadIdx.x;
    int wv = tid >> 6, ln = tid & 63;
    int lm = ln & 15, lq = ln >> 4;
    int m0 = blockIdx.x * 128;
    int nb = blockIdx.y * 128;
    int m0w = m0 + (wv >> 1) * 64;
    int n0w = nb + (wv & 1) * 64;

    f32x4 acc[4][4];
#pragma unroll
    for (int i = 0; i < 4; ++i)
#pragma unroll
        for (int j = 0; j < 4; ++j) acc[i][j] = f32x4{0.f, 0.f, 0.f, 0.f};

    for (int k0 = 0; k0 < KCAT; k0 += 64) {
#pragma unroll
        for (int t = 0; t < 4; ++t) {
            int ci = t * 256 + tid;
            int r = ci >> 3, s = ci & 7;
            int cg = s ^ (r & 7);
            int row = m0 + r; if (row >= M) row = M - 1;
            async16(A + (size_t)row * KCAT + k0 + cg * 8,
                    (unsigned char*)As + ci * 16);
        }
#pragma unroll
        for (int t = 0; t < 4; ++t) {
            int ci = t * 256 + tid;
            int r = ci >> 3, s = ci & 7;
            int cg = s ^ (r & 7);
            async16(W + (size_t)(nb + r) * KCAT + k0 + cg * 8,
                    (unsigned char*)Bs + ci * 16);
        }
        __syncthreads();
#pragma unroll
        for (int kk = 0; kk < 2; ++kk) {
            bf16x8 a[4], b[4];
#pragma unroll
            for (int i = 0; i < 4; ++i) {
                int r = (wv >> 1) * 64 + i * 16 + lm;
                int c = kk * 4 + lq;
                int s = c ^ (r & 7);
                a[i] = *reinterpret_cast<const bf16x8*>(As + (r * 8 + s) * 8);
            }
#pragma unroll
            for (int j = 0; j < 4; ++j) {
                int r = (wv & 1) * 64 + j * 16 + lm;
                int c = kk * 4 + lq;
                int s = c ^ (r & 7);
                b[j] = *reinterpret_cast<const bf16x8*>(Bs + (r * 8 + s) * 8);
            }
#pragma unroll
            for (int i = 0; i < 4; ++i)
#pragma unroll
                for (int j = 0; j < 4; ++j)
                    acc[i][j] = __builtin_amdgcn_mfma_f32_16x16x32_bf16(a[i], b[j], acc[i][j], 0, 0, 0);
        }
        __syncthreads();
    }

#pragma unroll
    for (int i = 0; i < 4; ++i) {
#pragma unroll
        for (int r4 = 0; r4 < 4; ++r4) {
            int rr = m0w + i * 16 + lq * 4 + r4;
            if (rr >= M) continue;
            float wr = wrow ? wrow[rr] : 0.f;
#pragma unroll
            for (int j = 0; j < 4; ++j) {
                int col = n0w + j * 16 + lm;
                float v = acc[i][j][r4] + bias[col];
                v = v > 0.f ? v : 0.f;
                xout[(size_t)rr * xstride + col] = f2bf(v);
                if (vout) vout[(size_t)rr * xstride + col] = f2bf(v * wr);
            }
        }
    }
}

// ---------------- final projection: out = xc2 @ Wout^T + bout (fp32) --------
__global__ void out_kernel(const unsigned short* __restrict__ xc, const float* __restrict__ Wout,
                           const float* __restrict__ bout, float* __restrict__ out) {
    __shared__ float srow[4][D];
    int r = threadIdx.x >> 6;
    int o = threadIdx.x & 63;
    int c = blockIdx.x * 4 + r;
    for (int t = threadIdx.x; t < 4 * D; t += 256) {
        int rr = blockIdx.x * 4 + (t >> 8);
        unsigned short h = xc[(size_t)rr * D + (t & 255)];
        srow[t >> 8][t & 255] = __uint_as_float(((unsigned)h) << 16);
    }
    __syncthreads();
    float s = 0.f;
    const float* wo = Wout + o * D;
    for (int k = 0; k < D; ++k) s += srow[r][k] * wo[k];
    out[(size_t)c * NOUTD + o] = s + bout[o];
}

// ---------------- orchestration ---------------------------------------------
extern "C" void kernel_launch(void* const* d_in, const int* in_sizes, int n_in,
                              void* d_out, int out_size, void* d_ws, size_t ws_size,
                              hipStream_t stream) {
    const float* x_gene = (const float*)d_in[0];
    const float* x_cell = (const float*)d_in[1];
    const int*   src_g2c = (const int*)d_in[2];
    const int*   dst_g2c = (const int*)d_in[3];
    const int*   src_c2g = (const int*)d_in[4];
    const int*   dst_c2g = (const int*)d_in[5];
    const float* w_g2c = (const float*)d_in[8];
    const float* w_c2g = (const float*)d_in[9];
    const float* w_gg  = (const float*)d_in[10];
    const float* w_cc  = (const float*)d_in[11];
    const float* Wrel  = (const float*)d_in[12];
    const float* brel  = (const float*)d_in[13];
    const float* Wroot = (const float*)d_in[14];
    const float* Wout  = (const float*)d_in[15];
    const float* bout  = (const float*)d_in[16];
    float* out = (float*)d_out;

    char* p = (char*)d_ws;
    auto alloc = [&](size_t bytes) -> char* {
        char* r = p;
        p += (bytes + 255) & ~(size_t)255;
        return r;
    };

    unsigned short* xg0b    = (unsigned short*)alloc((size_t)NG * D * 2);
    unsigned short* xg1     = (unsigned short*)alloc((size_t)NG * D * 2);
    unsigned short* agg_g   = (unsigned short*)alloc((size_t)NG * D * 2);
    unsigned short* Acat_c0 = (unsigned short*)alloc((size_t)NC * KCAT * 2);
    unsigned short* Acat_c1 = (unsigned short*)alloc((size_t)NC * KCAT * 2);
    unsigned short* xc2     = (unsigned short*)alloc((size_t)NC * D * 2);
    int* rp_g  = (int*)alloc((NG + 1) * 4);
    int* rp_c  = (int*)alloc((NC + 1) * 4);
    int2* ec = (int2*)alloc((size_t)NE * 8);       // g2c edges grouped by cell
    int2* eg = (int2*)alloc((size_t)NE * 8);       // c2g edges grouped by gene
    int2* st_c = (int2*)alloc((size_t)NE * 8);     // coarse-bucketed staging
    int2* st_g = (int2*)alloc((size_t)NE * 8);
    int* hist512 = (int*)alloc(512 * 4);
    int* cbase   = (int*)alloc(514 * 4);
    int* ccur_c  = (int*)alloc(256 * 4);
    int* ccur_g  = (int*)alloc(256 * 4);
    unsigned short* Wg0 = (unsigned short*)alloc((size_t)D * KCAT * 2);
    unsigned short* Wc0 = (unsigned short*)alloc((size_t)D * KCAT * 2);
    unsigned short* Wc1 = (unsigned short*)alloc((size_t)D * KCAT * 2);
    float* bg0 = (float*)alloc(D * 4);
    float* bc0 = (float*)alloc(D * 4);
    float* bc1 = (float*)alloc(D * 4);

    hipMemsetAsync(hist512, 0, 512 * 4, stream);

    // cell prep (x + v into Acat_c0 cols)
    prep_x<<<(NC * 64 + 255) / 256, 256, 0, stream>>>(x_cell, w_cc, Acat_c0 + 256, Acat_c0 + 512, KCAT, NC);

    // all 3 weight matrices in one launch
    build_wcat3<<<dim3((D * D + 255) / 256, 3), 256, 0, stream>>>(
        Wrel, Wroot, brel, Wg0, Wc0, Wc1, bg0, bc0, bc1);

    // ---- CSR build: coarse hist -> coarse scan -> 2-level binned scatter ----
    coarse_count<<<(NE + CC_CHUNK - 1) / CC_CHUNK, 256, 0, stream>>>(dst_g2c, dst_c2g, hist512);
    coarse_scan<<<1, 256, 0, stream>>>(hist512, cbase, ccur_c, ccur_g, rp_c, rp_g);
    const int P1B = (NE + P1_CHUNK - 1) / P1_CHUNK;
    bucket_pass1<<<dim3(P1B, 2), 256, 0, stream>>>(
        src_g2c, dst_g2c, w_g2c, ccur_c, st_c,
        src_c2g, dst_c2g, w_c2g, ccur_g, st_g);
    bucket_pass2<<<P2_CBLK + P2_GBLK, 256, 0, stream>>>(
        st_c, ec, rp_c, st_g, eg, rp_g, cbase);
    sort_cell_edges<<<NC, 256, 0, stream>>>(rp_c, ec);

    // ---- gene path ----
    agg_gene_conv<<<(NG + 3) / 4, 256, 0, stream>>>(
        rp_g, eg, Acat_c0 + 256, KCAT, x_gene, xg0b, agg_g, NG);
    gene_gemm<<<dim3((NG + 127) / 128, 2), 256, 0, stream>>>(
        agg_g, xg0b, w_gg, Wg0, bg0, xg1);

    // ---- Layer 0 cells ----
    agg_cell<<<NC, 256, 0, stream>>>(rp_c, ec, xg0b, D, Acat_c0, KCAT);
    gemm_tile<<<dim3((NC + 127) / 128, 2), 256, 0, stream>>>(
        Acat_c0, Wc0, bc0, w_cc, Acat_c1 + 256, KCAT, Acat_c1 + 512, NC);

    // ---- Layer 1 cells ----
    agg_cell<<<NC, 256, 0, stream>>>(rp_c, ec, xg1, D, Acat_c1, KCAT);
    gemm_tile<<<dim3((NC + 127) / 128, 2), 256, 0, stream>>>(
        Acat_c1, Wc1, bc1, nullptr, xc2, D, nullptr, NC);

    // ---- output projection ----
    out_kernel<<<NC / 4, 256, 0, stream>>>(xc2, Wout, bout, out);
}